// Round 4
// baseline (18591.472 us; speedup 1.0000x reference)
//
#include <hip/hip_runtime.h>

// Problem: VOCAB=10000, EMB=100, T=80, UNITS=256, BATCH=4096 — ALL FP32.
// out = sigmoid(h2_T);  h_l,t = tanh(x_l,t @ Wl + h_l,t-1 @ Ul + bl)
#define BATCH 4096
#define TLEN  80
#define EMBD  100
#define UNITS 256
#define RPB   8               // batch rows per block
#define GRID  (BATCH / RPB)   // 512 blocks

typedef __attribute__((ext_vector_type(4))) float f4;

// clamped: no NaN/inf even on garbage input; accurate to ~1e-6 in range
__device__ __forceinline__ float fast_tanh(float x) {
  x = fminf(fmaxf(x, -15.f), 15.f);
  float e = __expf(-2.f * x);
  return (1.f - e) / (1.f + e);
}
__device__ __forceinline__ float fast_sigmoid(float x) {
  x = fminf(fmaxf(x, -30.f), 30.f);
  return 1.f / (1.f + __expf(-x));
}

// One fused kernel, NO workspace. Block = 256 threads = 8 rows x 32 col-octets.
// Thread owns 1 row (r = tid>>5) x 8 cols (c8 = (tid&31)*8).
// LDS: sh1/sh2 fp32 states (8 KB each) + sx embedding stage (3.2 KB) = 19.2 KB.
// Weights stay in global (870 KB fp32 total, L2-resident; per-wave reads are
// 2 unique 1 KB rows -> L1 broadcast absorbs the row-group duplication).
__global__ __launch_bounds__(256) void rnn_fused(
    const int* __restrict__ idx, const float* __restrict__ emb,
    const float* __restrict__ W1, const float* __restrict__ U1, const float* __restrict__ b1,
    const float* __restrict__ W2, const float* __restrict__ U2, const float* __restrict__ b2,
    float* __restrict__ out)
{
  __shared__ float sh1[RPB][UNITS];
  __shared__ float sh2[RPB][UNITS];
  __shared__ float sx [RPB][EMBD];   // EMBD*4 = 400 B rows, 16B-aligned

  const int tid = threadIdx.x;
  const int c8  = (tid & 31) * 8;    // column octet
  const int r   = tid >> 5;          // row within block, 0..7
  const int b0  = blockIdx.x * RPB;

  float bias1[8], bias2[8];
#pragma unroll
  for (int j = 0; j < 8; ++j) { bias1[j] = b1[c8 + j]; bias2[j] = b2[c8 + j]; }

  // init states + stage embeddings for t=0
#pragma unroll
  for (int j = 0; j < 8; ++j) { sh1[r][c8 + j] = 0.f; sh2[r][c8 + j] = 0.f; }
  for (int i = tid; i < RPB * EMBD; i += 256) {
    int rr = i / EMBD, k = i - rr * EMBD;
    int tok = idx[(b0 + rr) * TLEN + 0];
    sx[rr][k] = emb[tok * EMBD + k];
  }
  __syncthreads();                                  // A (t=0)

  float th2[8];
  for (int t = 0; t < TLEN; ++t) {
    // ---- layer 1: a = b1 + x_t @ W1 + h1 @ U1 ----
    float a[8];
#pragma unroll
    for (int j = 0; j < 8; ++j) a[j] = bias1[j];
    for (int k = 0; k < EMBD; k += 4) {             // 25 iterations exact
      f4 h4 = *(const f4*)&sx[r][k];
#pragma unroll
      for (int j = 0; j < 4; ++j) {
        const f4* w = (const f4*)&W1[(k + j) * UNITS + c8];
        f4 w0 = w[0], w1 = w[1];
        float h = h4[j];
        a[0] += h * w0[0]; a[1] += h * w0[1]; a[2] += h * w0[2]; a[3] += h * w0[3];
        a[4] += h * w1[0]; a[5] += h * w1[1]; a[6] += h * w1[2]; a[7] += h * w1[3];
      }
    }
    for (int k = 0; k < UNITS; k += 4) {
      f4 h4 = *(const f4*)&sh1[r][k];
#pragma unroll
      for (int j = 0; j < 4; ++j) {
        const f4* w = (const f4*)&U1[(k + j) * UNITS + c8];
        f4 w0 = w[0], w1 = w[1];
        float h = h4[j];
        a[0] += h * w0[0]; a[1] += h * w0[1]; a[2] += h * w0[2]; a[3] += h * w0[3];
        a[4] += h * w1[0]; a[5] += h * w1[1]; a[6] += h * w1[2]; a[7] += h * w1[3];
      }
    }
    __syncthreads();                                // B: old sh1/sx reads done
#pragma unroll
    for (int j = 0; j < 8; ++j) sh1[r][c8 + j] = fast_tanh(a[j]);
    __syncthreads();                                // C: new sh1 visible

    // ---- layer 2: a = b2 + h1_t @ W2 + h2 @ U2 ----
#pragma unroll
    for (int j = 0; j < 8; ++j) a[j] = bias2[j];
    for (int k = 0; k < UNITS; k += 4) {
      f4 h14 = *(const f4*)&sh1[r][k];
      f4 h24 = *(const f4*)&sh2[r][k];
#pragma unroll
      for (int j = 0; j < 4; ++j) {
        const f4* w2 = (const f4*)&W2[(k + j) * UNITS + c8];
        const f4* u2 = (const f4*)&U2[(k + j) * UNITS + c8];
        f4 w20 = w2[0], w21 = w2[1], u20 = u2[0], u21 = u2[1];
        float g1 = h14[j], g2 = h24[j];
        a[0] += g1 * w20[0] + g2 * u20[0];
        a[1] += g1 * w20[1] + g2 * u20[1];
        a[2] += g1 * w20[2] + g2 * u20[2];
        a[3] += g1 * w20[3] + g2 * u20[3];
        a[4] += g1 * w21[0] + g2 * u21[0];
        a[5] += g1 * w21[1] + g2 * u21[1];
        a[6] += g1 * w21[2] + g2 * u21[2];
        a[7] += g1 * w21[3] + g2 * u21[3];
      }
    }
    __syncthreads();                                // D: old sh2 reads done
#pragma unroll
    for (int j = 0; j < 8; ++j) { th2[j] = fast_tanh(a[j]); sh2[r][c8 + j] = th2[j]; }
    if (t + 1 < TLEN) {                             // stage x for t+1 (sx dead since B)
      for (int i = tid; i < RPB * EMBD; i += 256) {
        int rr = i / EMBD, k = i - rr * EMBD;
        int tok = idx[(b0 + rr) * TLEN + (t + 1)];
        sx[rr][k] = emb[tok * EMBD + k];
      }
    }
    __syncthreads();                                // A: sh2 + sx visible
  }

  // epilogue: out = sigmoid(h2_T)  (fp32 stores)
  f4 o0, o1;
#pragma unroll
  for (int j = 0; j < 4; ++j) {
    o0[j] = fast_sigmoid(th2[j]);
    o1[j] = fast_sigmoid(th2[4 + j]);
  }
  *(f4*)&out[(b0 + r) * UNITS + c8]     = o0;
  *(f4*)&out[(b0 + r) * UNITS + c8 + 4] = o1;
}

extern "C" void kernel_launch(void* const* d_in, const int* in_sizes, int n_in,
                              void* d_out, int out_size, void* d_ws, size_t ws_size,
                              hipStream_t stream)
{
  const int*   idx = (const int*)d_in[0];
  const float* emb = (const float*)d_in[1];
  const float* W1  = (const float*)d_in[2];
  const float* U1  = (const float*)d_in[3];
  const float* b1  = (const float*)d_in[4];
  const float* W2  = (const float*)d_in[5];
  const float* U2  = (const float*)d_in[6];
  const float* b2  = (const float*)d_in[7];
  // d_in[8] (Wd), d_in[9] (bd) are dead in the reference output.
  (void)d_ws; (void)ws_size;

  rnn_fused<<<GRID, 256, 0, stream>>>(idx, emb, W1, U1, b1, W2, U2, b2,
                                      (float*)d_out);
}

// Round 5
// 14667.612 us; speedup vs baseline: 1.2675x; 1.2675x over previous
//
#include <hip/hip_runtime.h>

// Problem: VOCAB=10000, EMB=100, T=80, UNITS=256, BATCH=4096 — ALL FP32.
// out = sigmoid(h2_T);  h_l,t = tanh(x_l,t @ Wl + h_l,t-1 @ Ul + bl)
#define BATCH 4096
#define TLEN  80
#define EMBD  100
#define UNITS 256
#define RPB   8                // batch rows per block
#define GRID  (BATCH / RPB)    // 512 blocks = 2 blocks/CU
#define PADU  260              // padded LDS row stride (floats)
#define PADE  104

typedef __attribute__((ext_vector_type(4))) float f4;

__device__ __forceinline__ float fast_tanh(float x) {
  x = fminf(fmaxf(x, -15.f), 15.f);
  float e = __expf(-2.f * x);
  return (1.f - e) / (1.f + e);
}
__device__ __forceinline__ float fast_sigmoid(float x) {
  x = fminf(fmaxf(x, -30.f), 30.f);
  return 1.f / (1.f + __expf(-x));
}

// ---- pipelined k-loops: load chunk k+1 before FMA of chunk k ---------------
// acc[8] += sum_k hrow[k] * Wc[k*UNITS + {0..7}]   (Wc pre-offset by c8)

// K=100, chunk=4 (25 chunks)
__device__ __forceinline__ void mac_k100(float a[8], const float* __restrict__ Wc,
                                         const float* __restrict__ hrow)
{
  f4 hc = *(const f4*)&hrow[0];
  f4 wc[4][2];
#pragma unroll
  for (int j = 0; j < 4; ++j) {
    wc[j][0] = *(const f4*)&Wc[j * UNITS];
    wc[j][1] = *(const f4*)&Wc[j * UNITS + 4];
  }
  for (int kb = 0; kb < EMBD; kb += 4) {
    f4 hn; f4 wn[4][2];
    const bool more = (kb + 4 < EMBD);
    if (more) {                               // issue next chunk's loads first
      hn = *(const f4*)&hrow[kb + 4];
#pragma unroll
      for (int j = 0; j < 4; ++j) {
        wn[j][0] = *(const f4*)&Wc[(kb + 4 + j) * UNITS];
        wn[j][1] = *(const f4*)&Wc[(kb + 4 + j) * UNITS + 4];
      }
    }
#pragma unroll
    for (int j = 0; j < 4; ++j) {             // consume current chunk
      float h = hc[j];
      a[0] += h * wc[j][0][0]; a[1] += h * wc[j][0][1];
      a[2] += h * wc[j][0][2]; a[3] += h * wc[j][0][3];
      a[4] += h * wc[j][1][0]; a[5] += h * wc[j][1][1];
      a[6] += h * wc[j][1][2]; a[7] += h * wc[j][1][3];
    }
    if (more) {
      hc = hn;
#pragma unroll
      for (int j = 0; j < 4; ++j) { wc[j][0] = wn[j][0]; wc[j][1] = wn[j][1]; }
    }
  }
}

// K=256, chunk=8 (32 chunks, 17 loads in flight)
__device__ __forceinline__ void mac_k256(float a[8], const float* __restrict__ Wc,
                                         const float* __restrict__ hrow)
{
  f4 hc0 = *(const f4*)&hrow[0];
  f4 hc1 = *(const f4*)&hrow[4];
  f4 wc[8][2];
#pragma unroll
  for (int j = 0; j < 8; ++j) {
    wc[j][0] = *(const f4*)&Wc[j * UNITS];
    wc[j][1] = *(const f4*)&Wc[j * UNITS + 4];
  }
  for (int kb = 0; kb < UNITS; kb += 8) {
    f4 hn0, hn1; f4 wn[8][2];
    const bool more = (kb + 8 < UNITS);
    if (more) {
      hn0 = *(const f4*)&hrow[kb + 8];
      hn1 = *(const f4*)&hrow[kb + 12];
#pragma unroll
      for (int j = 0; j < 8; ++j) {
        wn[j][0] = *(const f4*)&Wc[(kb + 8 + j) * UNITS];
        wn[j][1] = *(const f4*)&Wc[(kb + 8 + j) * UNITS + 4];
      }
    }
#pragma unroll
    for (int j = 0; j < 8; ++j) {
      float h = (j < 4) ? hc0[j] : hc1[j - 4];
      a[0] += h * wc[j][0][0]; a[1] += h * wc[j][0][1];
      a[2] += h * wc[j][0][2]; a[3] += h * wc[j][0][3];
      a[4] += h * wc[j][1][0]; a[5] += h * wc[j][1][1];
      a[6] += h * wc[j][1][2]; a[7] += h * wc[j][1][3];
    }
    if (more) {
      hc0 = hn0; hc1 = hn1;
#pragma unroll
      for (int j = 0; j < 8; ++j) { wc[j][0] = wn[j][0]; wc[j][1] = wn[j][1]; }
    }
  }
}

// dual-matrix K=256, chunk=4: a += h1@W2 + h2@U2
__device__ __forceinline__ void mac_dual(float a[8],
                                         const float* __restrict__ W2c,
                                         const float* __restrict__ U2c,
                                         const float* __restrict__ h1row,
                                         const float* __restrict__ h2row)
{
  f4 g1 = *(const f4*)&h1row[0];
  f4 g2 = *(const f4*)&h2row[0];
  f4 wc[4][2], uc[4][2];
#pragma unroll
  for (int j = 0; j < 4; ++j) {
    wc[j][0] = *(const f4*)&W2c[j * UNITS];
    wc[j][1] = *(const f4*)&W2c[j * UNITS + 4];
    uc[j][0] = *(const f4*)&U2c[j * UNITS];
    uc[j][1] = *(const f4*)&U2c[j * UNITS + 4];
  }
  for (int kb = 0; kb < UNITS; kb += 4) {
    f4 g1n, g2n; f4 wn[4][2], un[4][2];
    const bool more = (kb + 4 < UNITS);
    if (more) {
      g1n = *(const f4*)&h1row[kb + 4];
      g2n = *(const f4*)&h2row[kb + 4];
#pragma unroll
      for (int j = 0; j < 4; ++j) {
        wn[j][0] = *(const f4*)&W2c[(kb + 4 + j) * UNITS];
        wn[j][1] = *(const f4*)&W2c[(kb + 4 + j) * UNITS + 4];
        un[j][0] = *(const f4*)&U2c[(kb + 4 + j) * UNITS];
        un[j][1] = *(const f4*)&U2c[(kb + 4 + j) * UNITS + 4];
      }
    }
#pragma unroll
    for (int j = 0; j < 4; ++j) {
      float x1 = g1[j], x2 = g2[j];
      a[0] += x1 * wc[j][0][0] + x2 * uc[j][0][0];
      a[1] += x1 * wc[j][0][1] + x2 * uc[j][0][1];
      a[2] += x1 * wc[j][0][2] + x2 * uc[j][0][2];
      a[3] += x1 * wc[j][0][3] + x2 * uc[j][0][3];
      a[4] += x1 * wc[j][1][0] + x2 * uc[j][1][0];
      a[5] += x1 * wc[j][1][1] + x2 * uc[j][1][1];
      a[6] += x1 * wc[j][1][2] + x2 * uc[j][1][2];
      a[7] += x1 * wc[j][1][3] + x2 * uc[j][1][3];
    }
    if (more) {
      g1 = g1n; g2 = g2n;
#pragma unroll
      for (int j = 0; j < 4; ++j) {
        wc[j][0] = wn[j][0]; wc[j][1] = wn[j][1];
        uc[j][0] = un[j][0]; uc[j][1] = un[j][1];
      }
    }
  }
}

// ---------------------------------------------------------------------------
// Fused kernel: block = 256 thr = 8 rows x 32 col-octets; thread = 1 row x 8 cols.
// Double-buffered LDS states -> 2 barriers/step.
// ---------------------------------------------------------------------------
__global__ __launch_bounds__(256, 2) void rnn_fused(
    const int* __restrict__ idx, const float* __restrict__ emb,
    const float* __restrict__ W1, const float* __restrict__ U1, const float* __restrict__ b1,
    const float* __restrict__ W2, const float* __restrict__ U2, const float* __restrict__ b2,
    float* __restrict__ out)
{
  __shared__ float sh1[2][RPB][PADU];   // 16.6 KB
  __shared__ float sh2[2][RPB][PADU];   // 16.6 KB
  __shared__ float sx [2][RPB][PADE];   //  6.7 KB

  const int tid = threadIdx.x;
  const int c8  = (tid & 31) * 8;
  const int r   = tid >> 5;
  const int b0  = blockIdx.x * RPB;

  const float* W1c = W1 + c8;
  const float* U1c = U1 + c8;
  const float* W2c = W2 + c8;
  const float* U2c = U2 + c8;

  float bias1[8], bias2[8];
#pragma unroll
  for (int j = 0; j < 8; ++j) { bias1[j] = b1[c8 + j]; bias2[j] = b2[c8 + j]; }

  // init: zero states (buffer 0), stage embeddings for t=0 into sx[0]
#pragma unroll
  for (int j = 0; j < 8; ++j) { sh1[0][r][c8 + j] = 0.f; sh2[0][r][c8 + j] = 0.f; }
  for (int i = tid; i < RPB * EMBD; i += 256) {
    int rr = i / EMBD, kk = i - rr * EMBD;
    sx[0][rr][kk] = emb[idx[(b0 + rr) * TLEN + 0] * EMBD + kk];
  }
  __syncthreads();

  float th2[8];
  for (int t = 0; t < TLEN; ++t) {
    const int p = t & 1, q = p ^ 1;

    // ---- layer 1: reads sx[p], sh1[p]; writes sh1[q] ----
    float a[8];
#pragma unroll
    for (int j = 0; j < 8; ++j) a[j] = bias1[j];
    mac_k100(a, W1c, &sx[p][r][0]);
    mac_k256(a, U1c, &sh1[p][r][0]);
#pragma unroll
    for (int j = 0; j < 8; ++j) sh1[q][r][c8 + j] = fast_tanh(a[j]);
    __syncthreads();                         // new h1 visible

    // ---- layer 2: reads sh1[q], sh2[p]; writes sh2[q]; stages sx[q] ----
    float b[8];
#pragma unroll
    for (int j = 0; j < 8; ++j) b[j] = bias2[j];
    mac_dual(b, W2c, U2c, &sh1[q][r][0], &sh2[p][r][0]);
#pragma unroll
    for (int j = 0; j < 8; ++j) { th2[j] = fast_tanh(b[j]); sh2[q][r][c8 + j] = th2[j]; }
    if (t + 1 < TLEN) {
      for (int i = tid; i < RPB * EMBD; i += 256) {
        int rr = i / EMBD, kk = i - rr * EMBD;
        sx[q][rr][kk] = emb[idx[(b0 + rr) * TLEN + (t + 1)] * EMBD + kk];
      }
    }
    __syncthreads();                         // sh2[q] + sx[q] visible
  }

  // epilogue: out = sigmoid(h2_T)
  f4 o0, o1;
#pragma unroll
  for (int j = 0; j < 4; ++j) {
    o0[j] = fast_sigmoid(th2[j]);
    o1[j] = fast_sigmoid(th2[4 + j]);
  }
  *(f4*)&out[(b0 + r) * UNITS + c8]     = o0;
  *(f4*)&out[(b0 + r) * UNITS + c8 + 4] = o1;
}

extern "C" void kernel_launch(void* const* d_in, const int* in_sizes, int n_in,
                              void* d_out, int out_size, void* d_ws, size_t ws_size,
                              hipStream_t stream)
{
  const int*   idx = (const int*)d_in[0];
  const float* emb = (const float*)d_in[1];
  const float* W1  = (const float*)d_in[2];
  const float* U1  = (const float*)d_in[3];
  const float* b1  = (const float*)d_in[4];
  const float* W2  = (const float*)d_in[5];
  const float* U2  = (const float*)d_in[6];
  const float* b2  = (const float*)d_in[7];
  // d_in[8] (Wd), d_in[9] (bd) are dead in the reference output.
  (void)d_ws; (void)ws_size;

  rnn_fused<<<GRID, 256, 0, stream>>>(idx, emb, W1, U1, b1, W2, U2, b2,
                                      (float*)d_out);
}

// Round 6
// 2800.421 us; speedup vs baseline: 6.6388x; 5.2376x over previous
//
#include <hip/hip_runtime.h>

// Problem: VOCAB=10000, EMB=100, T=80, UNITS=256, BATCH=4096 — ALL FP32.
// out = sigmoid(h2_T);  h_l,t = tanh(x_l,t @ Wl + h_l,t-1 @ Ul + bl)
#define BATCH 4096
#define TLEN  80
#define EMBD  100
#define UNITS 256
#define RPB   8                 // batch rows per block
#define GRID  (BATCH / RPB)     // 512 blocks = 2 blocks/CU
#define RS    260               // padded state row stride (floats, mult of 4)
#define XS    104               // padded embedding row stride

typedef __attribute__((ext_vector_type(4))) float f4;
#define F4(p) (*(const f4*)(p))

__device__ __forceinline__ float fast_tanh(float x) {
  x = fminf(fmaxf(x, -15.f), 15.f);
  float e = __expf(-2.f * x);
  return (1.f - e) / (1.f + e);
}
__device__ __forceinline__ float fast_sigmoid(float x) {
  x = fminf(fmaxf(x, -30.f), 30.f);
  return 1.f / (1.f + __expf(-x));
}

// acc[8 rows][8 cols] += S[r][k] * Wc[k*UNITS + {0..7}] over k in [klo,khi).
// Wc pre-offset by col-octet. S = LDS state base, row stride STRIDE.
// 64 FMA per k vs 32 B global + 8 B-broadcast LDS -> 0.5 B/FMA at L1.
template<int STRIDE>
__device__ __forceinline__ void mac8(float acc[8][8], const float* __restrict__ Wc,
                                     const float* __restrict__ S, int klo, int khi)
{
  if (klo >= khi) return;
  f4 w0 = F4(Wc + (size_t)klo * UNITS);
  f4 w1 = F4(Wc + (size_t)klo * UNITS + 4);
  float hb[8];
#pragma unroll
  for (int r = 0; r < 8; ++r) hb[r] = S[r * STRIDE + klo];
  for (int k = klo; k < khi; ++k) {
    f4 nw0, nw1; float nh[8];
    if (k + 1 < khi) {                      // prefetch next k (regs, not used yet)
      nw0 = F4(Wc + (size_t)(k + 1) * UNITS);
      nw1 = F4(Wc + (size_t)(k + 1) * UNITS + 4);
#pragma unroll
      for (int r = 0; r < 8; ++r) nh[r] = S[r * STRIDE + k + 1];
    }
#pragma unroll
    for (int r = 0; r < 8; ++r) {
      float h = hb[r];
      acc[r][0] += h * w0[0]; acc[r][1] += h * w0[1];
      acc[r][2] += h * w0[2]; acc[r][3] += h * w0[3];
      acc[r][4] += h * w1[0]; acc[r][5] += h * w1[1];
      acc[r][6] += h * w1[2]; acc[r][7] += h * w1[3];
    }
    w0 = nw0; w1 = nw1;
#pragma unroll
    for (int r = 0; r < 8; ++r) hb[r] = nh[r];
  }
}

// ---------------------------------------------------------------------------
// Fused 2-layer RNN, no workspace. Block = 256 thr = 32 col-octets x 8 k-slices.
// Thread (o,s): partial acc[8 rows][8 cols] over slice s's k-range.
// Reduce: shfl_xor(32) pairs slices in-wave -> red[4][8][RS] LDS -> owner
// thread (row=s, cols=c8) sums 4 partials + bias -> tanh -> state.
// LDS: sh1/sh2 dbuf 16.6 KB each + sx 6.7 KB + red 33.3 KB = 73.2 KB -> 2 blk/CU.
// ---------------------------------------------------------------------------
__global__ __launch_bounds__(256, 2) void rnn_fused(
    const int* __restrict__ idx, const float* __restrict__ emb,
    const float* __restrict__ W1, const float* __restrict__ U1, const float* __restrict__ b1,
    const float* __restrict__ W2, const float* __restrict__ U2, const float* __restrict__ b2,
    float* __restrict__ out)
{
  __shared__ float sh1[2][RPB][RS];
  __shared__ float sh2[2][RPB][RS];
  __shared__ float sx [2][RPB][XS];
  __shared__ float red[4][RPB][RS];

  const int tid = threadIdx.x;
  const int o   = tid & 31;         // col-octet
  const int s   = tid >> 5;         // k-slice (also owned row in reduce phase)
  const int c8  = o * 8;
  const int wv  = tid >> 6;         // wave id = slice-pair id
  const int b0  = blockIdx.x * RPB;

  // k-ranges for this slice
  const int k1lo = s * 13, k1hi = (k1lo + 13 < EMBD) ? k1lo + 13 : EMBD;  // K=100
  const int k2lo = s * 32, k2hi = k2lo + 32;                              // K=256

  const float* W1c = W1 + c8;
  const float* U1c = U1 + c8;
  const float* W2c = W2 + c8;
  const float* U2c = U2 + c8;

  float bias1[8], bias2[8];
#pragma unroll
  for (int j = 0; j < 8; ++j) { bias1[j] = b1[c8 + j]; bias2[j] = b2[c8 + j]; }

  // init states (buffer 0) + stage embeddings for t=0
  for (int i = tid; i < RPB * RS; i += 256) {
    (&sh1[0][0][0])[i] = 0.f;
    (&sh2[0][0][0])[i] = 0.f;
  }
  for (int i = tid; i < RPB * EMBD; i += 256) {
    int rr = i / EMBD, kk = i - rr * EMBD;
    sx[0][rr][kk] = emb[idx[(b0 + rr) * TLEN + 0] * EMBD + kk];
  }
  __syncthreads();

  for (int t = 0; t < TLEN; ++t) {
    const int p = t & 1, q = p ^ 1;

    // ======== layer 1: a = b1 + x_t @ W1 + h1 @ U1 ========
    float acc[8][8];
#pragma unroll
    for (int r = 0; r < 8; ++r)
#pragma unroll
      for (int j = 0; j < 8; ++j) acc[r][j] = 0.f;

    mac8<XS>(acc, W1c, &sx[p][0][0],  k1lo, k1hi);
    mac8<RS>(acc, U1c, &sh1[p][0][0], k2lo, k2hi);

    // reduce slices: pair in-wave, then LDS
#pragma unroll
    for (int r = 0; r < 8; ++r)
#pragma unroll
      for (int j = 0; j < 8; ++j)
        acc[r][j] += __shfl_xor(acc[r][j], 32, 64);
    if ((tid & 63) < 32) {
#pragma unroll
      for (int r = 0; r < 8; ++r) {
        f4 v0 = {acc[r][0], acc[r][1], acc[r][2], acc[r][3]};
        f4 v1 = {acc[r][4], acc[r][5], acc[r][6], acc[r][7]};
        *(f4*)&red[wv][r][c8]     = v0;
        *(f4*)&red[wv][r][c8 + 4] = v1;
      }
    }
    __syncthreads();                                   // B1: red complete

    {  // owner phase: row = s, cols = c8..c8+7
      f4 a0 = F4(&red[0][s][c8])     ; f4 a1 = F4(&red[0][s][c8 + 4]);
      f4 t0 = F4(&red[1][s][c8])     ; f4 t1 = F4(&red[1][s][c8 + 4]);
      f4 u0 = F4(&red[2][s][c8])     ; f4 u1 = F4(&red[2][s][c8 + 4]);
      f4 v0 = F4(&red[3][s][c8])     ; f4 v1 = F4(&red[3][s][c8 + 4]);
      float h[8];
#pragma unroll
      for (int j = 0; j < 4; ++j) {
        h[j]     = fast_tanh(a0[j] + t0[j] + u0[j] + v0[j] + bias1[j]);
        h[4 + j] = fast_tanh(a1[j] + t1[j] + u1[j] + v1[j] + bias1[4 + j]);
      }
      f4 o0 = {h[0], h[1], h[2], h[3]}, o1 = {h[4], h[5], h[6], h[7]};
      *(f4*)&sh1[q][s][c8]     = o0;
      *(f4*)&sh1[q][s][c8 + 4] = o1;
    }
    __syncthreads();                                   // B2: new h1 visible

    // ======== layer 2: a = b2 + h1_t @ W2 + h2 @ U2 ========
#pragma unroll
    for (int r = 0; r < 8; ++r)
#pragma unroll
      for (int j = 0; j < 8; ++j) acc[r][j] = 0.f;

    mac8<RS>(acc, W2c, &sh1[q][0][0], k2lo, k2hi);
    mac8<RS>(acc, U2c, &sh2[p][0][0], k2lo, k2hi);

#pragma unroll
    for (int r = 0; r < 8; ++r)
#pragma unroll
      for (int j = 0; j < 8; ++j)
        acc[r][j] += __shfl_xor(acc[r][j], 32, 64);
    if ((tid & 63) < 32) {
#pragma unroll
      for (int r = 0; r < 8; ++r) {
        f4 v0 = {acc[r][0], acc[r][1], acc[r][2], acc[r][3]};
        f4 v1 = {acc[r][4], acc[r][5], acc[r][6], acc[r][7]};
        *(f4*)&red[wv][r][c8]     = v0;
        *(f4*)&red[wv][r][c8 + 4] = v1;
      }
    }
    // stage x for t+1 (sx[q] last read two barriers ago -> safe)
    if (t + 1 < TLEN) {
      for (int i = tid; i < RPB * EMBD; i += 256) {
        int rr = i / EMBD, kk = i - rr * EMBD;
        sx[q][rr][kk] = emb[idx[(b0 + rr) * TLEN + (t + 1)] * EMBD + kk];
      }
    }
    __syncthreads();                                   // B3: red + sx complete

    {  // owner phase
      f4 a0 = F4(&red[0][s][c8])     ; f4 a1 = F4(&red[0][s][c8 + 4]);
      f4 t0 = F4(&red[1][s][c8])     ; f4 t1 = F4(&red[1][s][c8 + 4]);
      f4 u0 = F4(&red[2][s][c8])     ; f4 u1 = F4(&red[2][s][c8 + 4]);
      f4 v0 = F4(&red[3][s][c8])     ; f4 v1 = F4(&red[3][s][c8 + 4]);
      float h[8];
#pragma unroll
      for (int j = 0; j < 4; ++j) {
        h[j]     = fast_tanh(a0[j] + t0[j] + u0[j] + v0[j] + bias2[j]);
        h[4 + j] = fast_tanh(a1[j] + t1[j] + u1[j] + v1[j] + bias2[4 + j]);
      }
      f4 o0 = {h[0], h[1], h[2], h[3]}, o1 = {h[4], h[5], h[6], h[7]};
      *(f4*)&sh2[q][s][c8]     = o0;
      *(f4*)&sh2[q][s][c8 + 4] = o1;
      if (t == TLEN - 1) {
        f4 g0, g1;
#pragma unroll
        for (int j = 0; j < 4; ++j) { g0[j] = fast_sigmoid(h[j]); g1[j] = fast_sigmoid(h[4 + j]); }
        *(f4*)&out[(b0 + s) * UNITS + c8]     = g0;
        *(f4*)&out[(b0 + s) * UNITS + c8 + 4] = g1;
      }
    }
    __syncthreads();                                   // B4: sh2[q] + red reuse safe
  }
}

extern "C" void kernel_launch(void* const* d_in, const int* in_sizes, int n_in,
                              void* d_out, int out_size, void* d_ws, size_t ws_size,
                              hipStream_t stream)
{
  const int*   idx = (const int*)d_in[0];
  const float* emb = (const float*)d_in[1];
  const float* W1  = (const float*)d_in[2];
  const float* U1  = (const float*)d_in[3];
  const float* b1  = (const float*)d_in[4];
  const float* W2  = (const float*)d_in[5];
  const float* U2  = (const float*)d_in[6];
  const float* b2  = (const float*)d_in[7];
  // d_in[8] (Wd), d_in[9] (bd) are dead in the reference output.
  (void)d_ws; (void)ws_size;

  rnn_fused<<<GRID, 256, 0, stream>>>(idx, emb, W1, U1, b1, W2, U2, b2,
                                      (float*)d_out);
}

// Round 7
// 2266.211 us; speedup vs baseline: 8.2038x; 1.2357x over previous
//
#include <hip/hip_runtime.h>

// Problem: VOCAB=10000, EMB=100, T=80, UNITS=256, BATCH=4096 — ALL FP32.
// out = sigmoid(h2_T);  h_l,t = tanh(x_l,t @ Wl + h_l,t-1 @ Ul + bl)
#define BATCH 4096
#define TLEN  80
#define EMBD  100
#define UNITS 256
#define EMB_PAD 128            // emb K padded to 4 k-tiles of 32

typedef unsigned short u16;
typedef __attribute__((ext_vector_type(8))) short short8;   // 8 bf16 (4 VGPR) MFMA A/B frag
typedef __attribute__((ext_vector_type(4))) float f32x4;    // MFMA C/D frag
typedef __attribute__((ext_vector_type(4))) float f4;

__device__ __forceinline__ float bf2f(u16 x) {
  union { unsigned int u; float f; } v; v.u = ((unsigned int)x) << 16; return v.f;
}
__device__ __forceinline__ u16 f2bf(float f) {
  union { float f; unsigned int u; } v; v.f = f;
  unsigned int r = v.u + 0x7fffu + ((v.u >> 16) & 1u);  // RNE
  return (u16)(r >> 16);
}
// v ≈ hi + lo with 16-bit effective mantissa (residual ~2^-17 relative)
__device__ __forceinline__ void split2(float v, u16& hi, u16& lo) {
  u16 h = f2bf(v);
  hi = h;
  lo = f2bf(v - bf2f(h));
}
__device__ __forceinline__ float fast_tanh(float x) {
  x = fminf(fmaxf(x, -15.f), 15.f);
  float e = __expf(-2.f * x);
  return (1.f - e) / (1.f + e);
}
__device__ __forceinline__ float fast_sigmoid(float x) {
  x = fminf(fmaxf(x, -30.f), 30.f);
  return 1.f / (1.f + __expf(-x));
}

// ---------------- workspace layout (bytes) ----------------
// emb hi/lo padded [10000][128] bf16, then weight B-frags hi/lo.
// B-frag layout (16x16x32 bf16): lane holds B[k=quad*8+j][n=lane&15], stored as
// 8 contiguous bf16 per (ktg,nt,lane) -> one dwordx4 per lane per MFMA.
// ktg slots: W1(K pad 128)=0..3, U1=4..11, W2=12..19, U2=20..27.
#define KT_ALL 28
#define OFF_EHI ((size_t)0)
#define OFF_ELO ((size_t)10000 * EMB_PAD * 2)
#define OFF_WHI (OFF_ELO * 2)
#define WFRAG_BYTES ((size_t)KT_ALL * 16 * 64 * 8 * 2)
#define OFF_WLO (OFF_WHI + WFRAG_BYTES)
#define WS_NEED (OFF_WLO + WFRAG_BYTES)          // 6,037,504 B

__device__ __forceinline__ size_t fidx(int ktg, int nt, int lane) {
  return (((size_t)ktg * 16 + nt) * 64 + lane) * 8;
}

// ---------------- precompute: emb -> padded bf16 hi/lo ----------------
__global__ __launch_bounds__(256) void k_split_emb(
    const float* __restrict__ emb, u16* __restrict__ ehi, u16* __restrict__ elo)
{
  int gid = blockIdx.x * 256 + threadIdx.x;          // over 10000*128
  if (gid >= 10000 * EMB_PAD) return;
  int row = gid >> 7, kk = gid & (EMB_PAD - 1);
  float v = (kk < EMBD) ? emb[row * EMBD + kk] : 0.f;
  u16 hi, lo; split2(v, hi, lo);
  ehi[gid] = hi; elo[gid] = lo;
}

// ---------------- precompute: weights -> swizzled bf16 hi/lo B-frags --------
__global__ __launch_bounds__(256) void k_split_w(
    const float* __restrict__ W1, const float* __restrict__ U1,
    const float* __restrict__ W2, const float* __restrict__ U2,
    u16* __restrict__ whi, u16* __restrict__ wlo)
{
  int gid = blockIdx.x * 256 + threadIdx.x;          // one per (ktg,nt,lane)
  if (gid >= KT_ALL * 16 * 64) return;
  int lane = gid & 63, nt = (gid >> 6) & 15, ktg = gid >> 10;
  const float* M; int Kact, ktl;
  if (ktg < 4)       { M = W1; Kact = EMBD;  ktl = ktg;      }
  else if (ktg < 12) { M = U1; Kact = UNITS; ktl = ktg - 4;  }
  else if (ktg < 20) { M = W2; Kact = UNITS; ktl = ktg - 12; }
  else               { M = U2; Kact = UNITS; ktl = ktg - 20; }
  int n = nt * 16 + (lane & 15);
  int kb = ktl * 32 + (lane >> 4) * 8;
  size_t base = fidx(ktg, nt, lane);
#pragma unroll
  for (int j = 0; j < 8; ++j) {
    int k = kb + j;
    float v = (k < Kact) ? M[(size_t)k * UNITS + n] : 0.f;
    u16 hi, lo; split2(v, hi, lo);
    whi[base + j] = hi; wlo[base + j] = lo;
  }
}

#define MFMA16(A, B, C) __builtin_amdgcn_mfma_f32_16x16x32_bf16(A, B, C, 0, 0, 0)

// write one tanh result into next-step A-frag arrays (hi/lo), frag coords:
// elem (row=m, col=k): kt=col>>5, lane'=((col>>3)&3)*16+row, j'=col&7
__device__ __forceinline__ void store_frag(u16* __restrict__ fh, u16* __restrict__ fl,
                                           int col, int row, float v) {
  int a = (col >> 5) * 512 + (((col >> 3) & 3) * 16 + row) * 8 + (col & 7);
  u16 hi, lo; split2(v, hi, lo);
  fh[a] = hi; fl[a] = lo;
}

// ---------------------------------------------------------------------------
// MFMA main kernel. Grid 256 blocks (16 batch rows each) x 512 thr (8 waves).
// Wave w owns n-tiles {2w, 2w+1} (cols [w*32, w*32+32)). 3-pass hi/lo MFMA:
// Whi*hhi + Whi*hlo + Wlo*hhi -> ~fp32 accuracy. h kept as bf16 hi/lo A-frags
// in LDS (double-buffered): 64 KB. Weight B-frags stream from ws (L2-resident,
// 917 KB/step/block = the L1/L2 floor ~550 us).
// ---------------------------------------------------------------------------
__global__ __launch_bounds__(512) void rnn_mfma(
    const int* __restrict__ idx,
    const u16* __restrict__ ehi, const u16* __restrict__ elo,
    const u16* __restrict__ whi, const u16* __restrict__ wlo,
    const float* __restrict__ b1, const float* __restrict__ b2,
    float* __restrict__ out)
{
  // [buf][hi/lo][kt*512 + lane*8 + j]
  __shared__ __align__(16) u16 f1[2][2][4096];
  __shared__ __align__(16) u16 f2[2][2][4096];

  const int tid  = threadIdx.x;
  const int lane = tid & 63;
  const int w    = tid >> 6;          // wave 0..7
  const int m    = lane & 15;
  const int q    = lane >> 4;
  const int nt0  = 2 * w, nt1 = 2 * w + 1;
  const int col0 = nt0 * 16 + m;
  const int col1 = col0 + 16;
  const int b0   = blockIdx.x * 16;

  const float bias1_0 = b1[col0], bias1_1 = b1[col1];
  const float bias2_0 = b2[col0], bias2_1 = b2[col1];
  const int* tokp = idx + (size_t)(b0 + m) * TLEN;

  for (int i = tid; i < 4096; i += 512) {
    f1[0][0][i] = 0; f1[0][1][i] = 0;
    f2[0][0][i] = 0; f2[0][1][i] = 0;
  }
  __syncthreads();

  for (int t = 0; t < TLEN; ++t) {
    const int p = t & 1, qb = p ^ 1;

    // ======== layer 1: x@W1 + h1@U1 ========
    f32x4 acc0 = (f32x4){0.f, 0.f, 0.f, 0.f};
    f32x4 acc1 = (f32x4){0.f, 0.f, 0.f, 0.f};
    const int tok = tokp[t];
    const u16* eh = ehi + (size_t)tok * EMB_PAD + q * 8;
    const u16* el = elo + (size_t)tok * EMB_PAD + q * 8;
#pragma unroll
    for (int kt = 0; kt < 4; ++kt) {                 // x-part (K pad 128)
      short8 ah  = *(const short8*)(eh + kt * 32);
      short8 al  = *(const short8*)(el + kt * 32);
      short8 bh0 = *(const short8*)(whi + fidx(kt, nt0, lane));
      short8 bl0 = *(const short8*)(wlo + fidx(kt, nt0, lane));
      short8 bh1 = *(const short8*)(whi + fidx(kt, nt1, lane));
      short8 bl1 = *(const short8*)(wlo + fidx(kt, nt1, lane));
      acc0 = MFMA16(ah, bh0, acc0); acc1 = MFMA16(ah, bh1, acc1);
      acc0 = MFMA16(al, bh0, acc0); acc1 = MFMA16(al, bh1, acc1);
      acc0 = MFMA16(ah, bl0, acc0); acc1 = MFMA16(ah, bl1, acc1);
    }
#pragma unroll
    for (int kt = 0; kt < 8; ++kt) {                 // U1-part
      const int e = kt * 512 + lane * 8;
      short8 ah  = *(const short8*)&f1[p][0][e];
      short8 al  = *(const short8*)&f1[p][1][e];
      short8 bh0 = *(const short8*)(whi + fidx(4 + kt, nt0, lane));
      short8 bl0 = *(const short8*)(wlo + fidx(4 + kt, nt0, lane));
      short8 bh1 = *(const short8*)(whi + fidx(4 + kt, nt1, lane));
      short8 bl1 = *(const short8*)(wlo + fidx(4 + kt, nt1, lane));
      acc0 = MFMA16(ah, bh0, acc0); acc1 = MFMA16(ah, bh1, acc1);
      acc0 = MFMA16(al, bh0, acc0); acc1 = MFMA16(al, bh1, acc1);
      acc0 = MFMA16(ah, bl0, acc0); acc1 = MFMA16(ah, bl1, acc1);
    }
    // epilogue 1: D rows q*4+r -> tanh -> f1[qb] frags
#pragma unroll
    for (int r = 0; r < 4; ++r) {
      int row = q * 4 + r;
      store_frag(f1[qb][0], f1[qb][1], col0, row, fast_tanh(acc0[r] + bias1_0));
      store_frag(f1[qb][0], f1[qb][1], col1, row, fast_tanh(acc1[r] + bias1_1));
    }
    __syncthreads();                                 // f1[qb] visible

    // ======== layer 2: h1@W2 + h2@U2 ========
    acc0 = (f32x4){0.f, 0.f, 0.f, 0.f};
    acc1 = (f32x4){0.f, 0.f, 0.f, 0.f};
#pragma unroll
    for (int kt = 0; kt < 8; ++kt) {                 // W2-part (A = h1 new)
      const int e = kt * 512 + lane * 8;
      short8 ah  = *(const short8*)&f1[qb][0][e];
      short8 al  = *(const short8*)&f1[qb][1][e];
      short8 bh0 = *(const short8*)(whi + fidx(12 + kt, nt0, lane));
      short8 bl0 = *(const short8*)(wlo + fidx(12 + kt, nt0, lane));
      short8 bh1 = *(const short8*)(whi + fidx(12 + kt, nt1, lane));
      short8 bl1 = *(const short8*)(wlo + fidx(12 + kt, nt1, lane));
      acc0 = MFMA16(ah, bh0, acc0); acc1 = MFMA16(ah, bh1, acc1);
      acc0 = MFMA16(al, bh0, acc0); acc1 = MFMA16(al, bh1, acc1);
      acc0 = MFMA16(ah, bl0, acc0); acc1 = MFMA16(ah, bl1, acc1);
    }
#pragma unroll
    for (int kt = 0; kt < 8; ++kt) {                 // U2-part (A = h2 old)
      const int e = kt * 512 + lane * 8;
      short8 ah  = *(const short8*)&f2[p][0][e];
      short8 al  = *(const short8*)&f2[p][1][e];
      short8 bh0 = *(const short8*)(whi + fidx(20 + kt, nt0, lane));
      short8 bl0 = *(const short8*)(wlo + fidx(20 + kt, nt0, lane));
      short8 bh1 = *(const short8*)(whi + fidx(20 + kt, nt1, lane));
      short8 bl1 = *(const short8*)(wlo + fidx(20 + kt, nt1, lane));
      acc0 = MFMA16(ah, bh0, acc0); acc1 = MFMA16(ah, bh1, acc1);
      acc0 = MFMA16(al, bh0, acc0); acc1 = MFMA16(al, bh1, acc1);
      acc0 = MFMA16(ah, bl0, acc0); acc1 = MFMA16(ah, bl1, acc1);
    }
    // epilogue 2
#pragma unroll
    for (int r = 0; r < 4; ++r) {
      int row = q * 4 + r;
      float t0v = fast_tanh(acc0[r] + bias2_0);
      float t1v = fast_tanh(acc1[r] + bias2_1);
      store_frag(f2[qb][0], f2[qb][1], col0, row, t0v);
      store_frag(f2[qb][0], f2[qb][1], col1, row, t1v);
      if (t == TLEN - 1) {
        out[(size_t)(b0 + row) * UNITS + col0] = fast_sigmoid(t0v);
        out[(size_t)(b0 + row) * UNITS + col1] = fast_sigmoid(t1v);
      }
    }
    __syncthreads();                                 // f2[qb] visible
  }
}

// ===========================================================================
// Fallback (round-6 kernel, proven 2.8 ms) — used when ws_size < WS_NEED.
// ===========================================================================
#define RPB 8
#define RS  260
#define XS  104
#define F4P(p) (*(const f4*)(p))

template<int STRIDE>
__device__ __forceinline__ void mac8(float acc[8][8], const float* __restrict__ Wc,
                                     const float* __restrict__ S, int klo, int khi)
{
  if (klo >= khi) return;
  f4 w0 = F4P(Wc + (size_t)klo * UNITS);
  f4 w1 = F4P(Wc + (size_t)klo * UNITS + 4);
  float hb[8];
#pragma unroll
  for (int r = 0; r < 8; ++r) hb[r] = S[r * STRIDE + klo];
  for (int k = klo; k < khi; ++k) {
    f4 nw0, nw1; float nh[8];
    if (k + 1 < khi) {
      nw0 = F4P(Wc + (size_t)(k + 1) * UNITS);
      nw1 = F4P(Wc + (size_t)(k + 1) * UNITS + 4);
#pragma unroll
      for (int r = 0; r < 8; ++r) nh[r] = S[r * STRIDE + k + 1];
    }
#pragma unroll
    for (int r = 0; r < 8; ++r) {
      float h = hb[r];
      acc[r][0] += h * w0[0]; acc[r][1] += h * w0[1];
      acc[r][2] += h * w0[2]; acc[r][3] += h * w0[3];
      acc[r][4] += h * w1[0]; acc[r][5] += h * w1[1];
      acc[r][6] += h * w1[2]; acc[r][7] += h * w1[3];
    }
    w0 = nw0; w1 = nw1;
#pragma unroll
    for (int r = 0; r < 8; ++r) hb[r] = nh[r];
  }
}

__global__ __launch_bounds__(256, 2) void rnn_fused_fb(
    const int* __restrict__ idx, const float* __restrict__ emb,
    const float* __restrict__ W1, const float* __restrict__ U1, const float* __restrict__ b1,
    const float* __restrict__ W2, const float* __restrict__ U2, const float* __restrict__ b2,
    float* __restrict__ out)
{
  __shared__ float sh1[2][RPB][RS];
  __shared__ float sh2[2][RPB][RS];
  __shared__ float sx [2][RPB][XS];
  __shared__ float red[4][RPB][RS];

  const int tid = threadIdx.x;
  const int s   = tid >> 5;
  const int c8  = (tid & 31) * 8;
  const int wv  = tid >> 6;
  const int b0  = blockIdx.x * RPB;
  const int k1lo = s * 13, k1hi = (k1lo + 13 < EMBD) ? k1lo + 13 : EMBD;
  const int k2lo = s * 32, k2hi = k2lo + 32;
  const float* W1c = W1 + c8; const float* U1c = U1 + c8;
  const float* W2c = W2 + c8; const float* U2c = U2 + c8;
  float bias1[8], bias2[8];
#pragma unroll
  for (int j = 0; j < 8; ++j) { bias1[j] = b1[c8 + j]; bias2[j] = b2[c8 + j]; }
  for (int i = tid; i < RPB * RS; i += 256) { (&sh1[0][0][0])[i] = 0.f; (&sh2[0][0][0])[i] = 0.f; }
  for (int i = tid; i < RPB * EMBD; i += 256) {
    int rr = i / EMBD, kk = i - rr * EMBD;
    sx[0][rr][kk] = emb[idx[(b0 + rr) * TLEN + 0] * EMBD + kk];
  }
  __syncthreads();
  for (int t = 0; t < TLEN; ++t) {
    const int p = t & 1, qq = p ^ 1;
    float acc[8][8];
#pragma unroll
    for (int r = 0; r < 8; ++r)
#pragma unroll
      for (int j = 0; j < 8; ++j) acc[r][j] = 0.f;
    mac8<XS>(acc, W1c, &sx[p][0][0],  k1lo, k1hi);
    mac8<RS>(acc, U1c, &sh1[p][0][0], k2lo, k2hi);
#pragma unroll
    for (int r = 0; r < 8; ++r)
#pragma unroll
      for (int j = 0; j < 8; ++j) acc[r][j] += __shfl_xor(acc[r][j], 32, 64);
    if ((tid & 63) < 32) {
#pragma unroll
      for (int r = 0; r < 8; ++r) {
        f4 v0 = {acc[r][0], acc[r][1], acc[r][2], acc[r][3]};
        f4 v1 = {acc[r][4], acc[r][5], acc[r][6], acc[r][7]};
        *(f4*)&red[wv][r][c8] = v0; *(f4*)&red[wv][r][c8 + 4] = v1;
      }
    }
    __syncthreads();
    {
      f4 a0 = F4P(&red[0][s][c8]), a1 = F4P(&red[0][s][c8 + 4]);
      f4 t0 = F4P(&red[1][s][c8]), t1 = F4P(&red[1][s][c8 + 4]);
      f4 u0 = F4P(&red[2][s][c8]), u1 = F4P(&red[2][s][c8 + 4]);
      f4 v0 = F4P(&red[3][s][c8]), v1 = F4P(&red[3][s][c8 + 4]);
      float h[8];
#pragma unroll
      for (int j = 0; j < 4; ++j) {
        h[j]     = fast_tanh(a0[j] + t0[j] + u0[j] + v0[j] + bias1[j]);
        h[4 + j] = fast_tanh(a1[j] + t1[j] + u1[j] + v1[j] + bias1[4 + j]);
      }
      f4 o0 = {h[0], h[1], h[2], h[3]}, o1 = {h[4], h[5], h[6], h[7]};
      *(f4*)&sh1[qq][s][c8] = o0; *(f4*)&sh1[qq][s][c8 + 4] = o1;
    }
    __syncthreads();
#pragma unroll
    for (int r = 0; r < 8; ++r)
#pragma unroll
      for (int j = 0; j < 8; ++j) acc[r][j] = 0.f;
    mac8<RS>(acc, W2c, &sh1[qq][0][0], k2lo, k2hi);
    mac8<RS>(acc, U2c, &sh2[p][0][0],  k2lo, k2hi);
#pragma unroll
    for (int r = 0; r < 8; ++r)
#pragma unroll
      for (int j = 0; j < 8; ++j) acc[r][j] += __shfl_xor(acc[r][j], 32, 64);
    if ((tid & 63) < 32) {
#pragma unroll
      for (int r = 0; r < 8; ++r) {
        f4 v0 = {acc[r][0], acc[r][1], acc[r][2], acc[r][3]};
        f4 v1 = {acc[r][4], acc[r][5], acc[r][6], acc[r][7]};
        *(f4*)&red[wv][r][c8] = v0; *(f4*)&red[wv][r][c8 + 4] = v1;
      }
    }
    if (t + 1 < TLEN) {
      for (int i = tid; i < RPB * EMBD; i += 256) {
        int rr = i / EMBD, kk = i - rr * EMBD;
        sx[qq][rr][kk] = emb[idx[(b0 + rr) * TLEN + (t + 1)] * EMBD + kk];
      }
    }
    __syncthreads();
    {
      f4 a0 = F4P(&red[0][s][c8]), a1 = F4P(&red[0][s][c8 + 4]);
      f4 t0 = F4P(&red[1][s][c8]), t1 = F4P(&red[1][s][c8 + 4]);
      f4 u0 = F4P(&red[2][s][c8]), u1 = F4P(&red[2][s][c8 + 4]);
      f4 v0 = F4P(&red[3][s][c8]), v1 = F4P(&red[3][s][c8 + 4]);
      float h[8];
#pragma unroll
      for (int j = 0; j < 4; ++j) {
        h[j]     = fast_tanh(a0[j] + t0[j] + u0[j] + v0[j] + bias2[j]);
        h[4 + j] = fast_tanh(a1[j] + t1[j] + u1[j] + v1[j] + bias2[4 + j]);
      }
      f4 o0 = {h[0], h[1], h[2], h[3]}, o1 = {h[4], h[5], h[6], h[7]};
      *(f4*)&sh2[qq][s][c8] = o0; *(f4*)&sh2[qq][s][c8 + 4] = o1;
      if (t == TLEN - 1) {
        f4 g0, g1;
#pragma unroll
        for (int j = 0; j < 4; ++j) { g0[j] = fast_sigmoid(h[j]); g1[j] = fast_sigmoid(h[4 + j]); }
        *(f4*)&out[(b0 + s) * UNITS + c8]     = g0;
        *(f4*)&out[(b0 + s) * UNITS + c8 + 4] = g1;
      }
    }
    __syncthreads();
  }
}

// ---------------------------------------------------------------------------
extern "C" void kernel_launch(void* const* d_in, const int* in_sizes, int n_in,
                              void* d_out, int out_size, void* d_ws, size_t ws_size,
                              hipStream_t stream)
{
  const int*   idx = (const int*)d_in[0];
  const float* emb = (const float*)d_in[1];
  const float* W1  = (const float*)d_in[2];
  const float* U1  = (const float*)d_in[3];
  const float* b1  = (const float*)d_in[4];
  const float* W2  = (const float*)d_in[5];
  const float* U2  = (const float*)d_in[6];
  const float* b2  = (const float*)d_in[7];
  // d_in[8] (Wd), d_in[9] (bd) are dead in the reference output.
  float* out = (float*)d_out;

  if (ws_size >= WS_NEED) {
    u16* ehi = (u16*)((char*)d_ws + OFF_EHI);
    u16* elo = (u16*)((char*)d_ws + OFF_ELO);
    u16* whi = (u16*)((char*)d_ws + OFF_WHI);
    u16* wlo = (u16*)((char*)d_ws + OFF_WLO);
    k_split_emb<<<(10000 * EMB_PAD + 255) / 256, 256, 0, stream>>>(emb, ehi, elo);
    k_split_w<<<(KT_ALL * 16 * 64 + 255) / 256, 256, 0, stream>>>(W1, U1, W2, U2, whi, wlo);
    rnn_mfma<<<BATCH / 16, 512, 0, stream>>>(idx, ehi, elo, whi, wlo, b1, b2, out);
  } else {
    rnn_fused_fb<<<BATCH / RPB, 256, 0, stream>>>(idx, emb, W1, U1, b1, W2, U2, b2, out);
  }
}

// Round 8
// 2082.875 us; speedup vs baseline: 8.9259x; 1.0880x over previous
//
#include <hip/hip_runtime.h>

// Problem: VOCAB=10000, EMB=100, T=80, UNITS=256, BATCH=4096 — ALL FP32.
// out = sigmoid(h2_T);  h_l,t = tanh(x_l,t @ Wl + h_l,t-1 @ Ul + bl)
#define BATCH 4096
#define TLEN  80
#define EMBD  100
#define UNITS 256
#define EMB_PAD 128            // emb K padded to 4 k-tiles of 32

typedef unsigned short u16;
typedef __attribute__((ext_vector_type(8))) short short8;   // 8 bf16 MFMA A/B frag
typedef __attribute__((ext_vector_type(4))) float f32x4;    // MFMA C/D frag
typedef __attribute__((ext_vector_type(4))) unsigned int u32x4;

__device__ __forceinline__ float bf2f(u16 x) {
  union { unsigned int u; float f; } v; v.u = ((unsigned int)x) << 16; return v.f;
}
__device__ __forceinline__ u16 f2bf(float f) {
  union { float f; unsigned int u; } v; v.f = f;
  unsigned int r = v.u + 0x7fffu + ((v.u >> 16) & 1u);  // RNE
  return (u16)(r >> 16);
}
// v ≈ hi + lo, 16-bit effective mantissa (residual ~2^-17 relative)
__device__ __forceinline__ void split2(float v, u16& hi, u16& lo) {
  u16 h = f2bf(v);
  hi = h;
  lo = f2bf(v - bf2f(h));
}
__device__ __forceinline__ float fast_tanh(float x) {
  x = fminf(fmaxf(x, -15.f), 15.f);
  float e = __expf(-2.f * x);
  return (1.f - e) / (1.f + e);
}
__device__ __forceinline__ float fast_sigmoid(float x) {
  x = fminf(fmaxf(x, -30.f), 30.f);
  return 1.f / (1.f + __expf(-x));
}
// non-temporal 16B load (nt flag: minimal L2 pollution) -> short8
__device__ __forceinline__ short8 ldnt8(const u16* p) {
  union { u32x4 u; short8 s; } v;
  v.u = __builtin_nontemporal_load((const u32x4*)p);
  return v.s;
}

// ---------------- workspace layout (unchanged from r7; ws >= 6 MB verified) --
// B-frag layout (16x16x32 bf16): lane holds B[k=quad*8+j][n=lane&15]; 8
// contiguous bf16 per (ktg,nt,lane) -> one dwordx4 per lane per MFMA.
// ktg slots: W1(K pad 128)=0..3, U1=4..11, W2=12..19, U2=20..27.
#define KT_ALL 28
#define OFF_EHI ((size_t)0)
#define OFF_ELO ((size_t)10000 * EMB_PAD * 2)
#define OFF_WHI (OFF_ELO * 2)
#define WFRAG_BYTES ((size_t)KT_ALL * 16 * 64 * 8 * 2)
#define OFF_WLO (OFF_WHI + WFRAG_BYTES)
#define WS_NEED (OFF_WLO + WFRAG_BYTES)          // 6,037,504 B (ws >= this, r7-verified)

__device__ __forceinline__ size_t fidx(int ktg, int nt, int lane) {
  return (((size_t)ktg * 16 + nt) * 64 + lane) * 8;
}

// ---------------- precompute: emb -> padded bf16 hi/lo (r7-verified) --------
__global__ __launch_bounds__(256) void k_split_emb(
    const float* __restrict__ emb, u16* __restrict__ ehi, u16* __restrict__ elo)
{
  int gid = blockIdx.x * 256 + threadIdx.x;
  if (gid >= 10000 * EMB_PAD) return;
  int row = gid >> 7, kk = gid & (EMB_PAD - 1);
  float v = (kk < EMBD) ? emb[row * EMBD + kk] : 0.f;
  u16 hi, lo; split2(v, hi, lo);
  ehi[gid] = hi; elo[gid] = lo;
}

// ---------------- precompute: weights -> swizzled bf16 hi/lo B-frags --------
__global__ __launch_bounds__(256) void k_split_w(
    const float* __restrict__ W1, const float* __restrict__ U1,
    const float* __restrict__ W2, const float* __restrict__ U2,
    u16* __restrict__ whi, u16* __restrict__ wlo)
{
  int gid = blockIdx.x * 256 + threadIdx.x;          // one per (ktg,nt,lane)
  if (gid >= KT_ALL * 16 * 64) return;
  int lane = gid & 63, nt = (gid >> 6) & 15, ktg = gid >> 10;
  const float* M; int Kact, ktl;
  if (ktg < 4)       { M = W1; Kact = EMBD;  ktl = ktg;      }
  else if (ktg < 12) { M = U1; Kact = UNITS; ktl = ktg - 4;  }
  else if (ktg < 20) { M = W2; Kact = UNITS; ktl = ktg - 12; }
  else               { M = U2; Kact = UNITS; ktl = ktg - 20; }
  int n = nt * 16 + (lane & 15);
  int kb = ktl * 32 + (lane >> 4) * 8;
  size_t base = fidx(ktg, nt, lane);
#pragma unroll
  for (int j = 0; j < 8; ++j) {
    int k = kb + j;
    float v = (k < Kact) ? M[(size_t)k * UNITS + n] : 0.f;
    u16 hi, lo; split2(v, hi, lo);
    whi[base + j] = hi; wlo[base + j] = lo;
  }
}

#define MFMA16(A, B, C) __builtin_amdgcn_mfma_f32_16x16x32_bf16(A, B, C, 0, 0, 0)

// write tanh result into next-step A-frag hi/lo (r7-verified layout):
// elem (row=m, col=k): kt=col>>5, lane'=((col>>3)&3)*16+row, j'=col&7
__device__ __forceinline__ void store_frag(u16* __restrict__ fh, u16* __restrict__ fl,
                                           int col, int row, float v) {
  int a = (col >> 5) * 512 + (((col >> 3) & 3) * 16 + row) * 8 + (col & 7);
  u16 hi, lo; split2(v, hi, lo);
  fh[a] = hi; fl[a] = lo;
}

// ---------------------------------------------------------------------------
// MFMA main kernel, v2: 256 blocks (16 batch rows) x 1024 thr (16 waves).
// Wave w owns n-tile w (cols [w*16, w*16+16)) — 1 nt/wave, 2x the waves of r7
// for 2x memory-level parallelism. 3-pass hi/lo MFMA (r7-verified numerics).
// h state bf16 hi/lo A-frags in LDS, double-buffered: 64 KB, 2 barriers/step.
// emb gathers use non-temporal loads to keep weight frags L2-resident.
// ---------------------------------------------------------------------------
__global__ __launch_bounds__(1024, 4) void rnn_mfma2(
    const int* __restrict__ idx,
    const u16* __restrict__ ehi, const u16* __restrict__ elo,
    const u16* __restrict__ whi, const u16* __restrict__ wlo,
    const float* __restrict__ b1, const float* __restrict__ b2,
    float* __restrict__ out)
{
  // [buf][hi/lo][kt*512 + lane*8 + j]
  __shared__ __align__(16) u16 f1[2][2][4096];
  __shared__ __align__(16) u16 f2[2][2][4096];

  const int tid  = threadIdx.x;
  const int lane = tid & 63;
  const int w    = tid >> 6;          // wave 0..15 = its n-tile
  const int m    = lane & 15;
  const int q    = lane >> 4;
  const int col0 = w * 16 + m;
  const int b0   = blockIdx.x * 16;

  const float bias1 = b1[col0];
  const float bias2 = b2[col0];
  const int* tokp = idx + (size_t)(b0 + m) * TLEN;

  for (int i = tid; i < 4096; i += 1024) {
    f1[0][0][i] = 0; f1[0][1][i] = 0;
    f2[0][0][i] = 0; f2[0][1][i] = 0;
  }
  __syncthreads();

  for (int t = 0; t < TLEN; ++t) {
    const int p = t & 1, qb = p ^ 1;

    // ======== layer 1: x@W1 + h1@U1 ========
    f32x4 acc = (f32x4){0.f, 0.f, 0.f, 0.f};
    const int tok = tokp[t];
    const u16* eh = ehi + (size_t)tok * EMB_PAD + q * 8;
    const u16* el = elo + (size_t)tok * EMB_PAD + q * 8;
#pragma unroll
    for (int kt = 0; kt < 4; ++kt) {                 // x-part (K pad 128)
      short8 ah = ldnt8(eh + kt * 32);               // non-temporal: no L2 pollution
      short8 al = ldnt8(el + kt * 32);
      short8 bh = *(const short8*)(whi + fidx(kt, w, lane));
      short8 bl = *(const short8*)(wlo + fidx(kt, w, lane));
      acc = MFMA16(ah, bh, acc);
      acc = MFMA16(al, bh, acc);
      acc = MFMA16(ah, bl, acc);
    }
#pragma unroll
    for (int kt = 0; kt < 8; ++kt) {                 // U1-part (A = h1 old)
      const int e = kt * 512 + lane * 8;
      short8 ah = *(const short8*)&f1[p][0][e];
      short8 al = *(const short8*)&f1[p][1][e];
      short8 bh = *(const short8*)(whi + fidx(4 + kt, w, lane));
      short8 bl = *(const short8*)(wlo + fidx(4 + kt, w, lane));
      acc = MFMA16(ah, bh, acc);
      acc = MFMA16(al, bh, acc);
      acc = MFMA16(ah, bl, acc);
    }
#pragma unroll
    for (int r = 0; r < 4; ++r)
      store_frag(f1[qb][0], f1[qb][1], col0, q * 4 + r, fast_tanh(acc[r] + bias1));
    __syncthreads();                                 // f1[qb] visible

    // ======== layer 2: h1@W2 + h2@U2 ========
    acc = (f32x4){0.f, 0.f, 0.f, 0.f};
#pragma unroll
    for (int kt = 0; kt < 8; ++kt) {                 // W2-part (A = h1 new)
      const int e = kt * 512 + lane * 8;
      short8 ah = *(const short8*)&f1[qb][0][e];
      short8 al = *(const short8*)&f1[qb][1][e];
      short8 bh = *(const short8*)(whi + fidx(12 + kt, w, lane));
      short8 bl = *(const short8*)(wlo + fidx(12 + kt, w, lane));
      acc = MFMA16(ah, bh, acc);
      acc = MFMA16(al, bh, acc);
      acc = MFMA16(ah, bl, acc);
    }
#pragma unroll
    for (int kt = 0; kt < 8; ++kt) {                 // U2-part (A = h2 old)
      const int e = kt * 512 + lane * 8;
      short8 ah = *(const short8*)&f2[p][0][e];
      short8 al = *(const short8*)&f2[p][1][e];
      short8 bh = *(const short8*)(whi + fidx(20 + kt, w, lane));
      short8 bl = *(const short8*)(wlo + fidx(20 + kt, w, lane));
      acc = MFMA16(ah, bh, acc);
      acc = MFMA16(al, bh, acc);
      acc = MFMA16(ah, bl, acc);
    }
#pragma unroll
    for (int r = 0; r < 4; ++r) {
      int row = q * 4 + r;
      float tv = fast_tanh(acc[r] + bias2);
      store_frag(f2[qb][0], f2[qb][1], col0, row, tv);
      if (t == TLEN - 1)
        out[(size_t)(b0 + row) * UNITS + col0] = fast_sigmoid(tv);
    }
    __syncthreads();                                 // f2[qb] visible
  }
}

// ---------------------------------------------------------------------------
extern "C" void kernel_launch(void* const* d_in, const int* in_sizes, int n_in,
                              void* d_out, int out_size, void* d_ws, size_t ws_size,
                              hipStream_t stream)
{
  const int*   idx = (const int*)d_in[0];
  const float* emb = (const float*)d_in[1];
  const float* W1  = (const float*)d_in[2];
  const float* U1  = (const float*)d_in[3];
  const float* b1  = (const float*)d_in[4];
  const float* W2  = (const float*)d_in[5];
  const float* U2  = (const float*)d_in[6];
  const float* b2  = (const float*)d_in[7];
  // d_in[8] (Wd), d_in[9] (bd) are dead in the reference output.
  float* out = (float*)d_out;

  // ws_size >= WS_NEED verified in round 7 (rnn_mfma ran on this harness).
  u16* ehi = (u16*)((char*)d_ws + OFF_EHI);
  u16* elo = (u16*)((char*)d_ws + OFF_ELO);
  u16* whi = (u16*)((char*)d_ws + OFF_WHI);
  u16* wlo = (u16*)((char*)d_ws + OFF_WLO);
  k_split_emb<<<(10000 * EMB_PAD + 255) / 256, 256, 0, stream>>>(emb, ehi, elo);
  k_split_w<<<(KT_ALL * 16 * 64 + 255) / 256, 256, 0, stream>>>(W1, U1, W2, U2, whi, wlo);
  rnn_mfma2<<<BATCH / 16, 1024, 0, stream>>>(idx, ehi, elo, whi, wlo, b1, b2, out);
}

// Round 9
// 1946.487 us; speedup vs baseline: 9.5513x; 1.0701x over previous
//
#include <hip/hip_runtime.h>

// Problem: VOCAB=10000, EMB=100, T=80, UNITS=256, BATCH=4096 — ALL FP32.
// out = sigmoid(h2_T);  h_l,t = tanh(x_l,t @ Wl + h_l,t-1 @ Ul + bl)
#define BATCH 4096
#define TLEN  80
#define EMBD  100
#define UNITS 256
#define BT    (BATCH * TLEN)
#define EMB_PAD 128

typedef unsigned short u16;
typedef __attribute__((ext_vector_type(8))) short short8;   // 8 bf16 MFMA A/B frag
typedef __attribute__((ext_vector_type(4))) float f32x4;    // MFMA C/D frag
typedef __attribute__((ext_vector_type(4))) float f4;

__device__ __forceinline__ float bf2f(u16 x) {
  union { unsigned int u; float f; } v; v.u = ((unsigned int)x) << 16; return v.f;
}
__device__ __forceinline__ u16 f2bf(float f) {
  union { float f; unsigned int u; } v; v.f = f;
  unsigned int r = v.u + 0x7fffu + ((v.u >> 16) & 1u);  // RNE
  return (u16)(r >> 16);
}
// v ≈ hi + lo, 16-bit effective mantissa (residual ~2^-17 relative)
__device__ __forceinline__ void split2(float v, u16& hi, u16& lo) {
  u16 h = f2bf(v);
  hi = h;
  lo = f2bf(v - bf2f(h));
}
__device__ __forceinline__ float fast_tanh(float x) {
  x = fminf(fmaxf(x, -15.f), 15.f);
  float e = __expf(-2.f * x);
  return (1.f - e) / (1.f + e);
}
__device__ __forceinline__ float fast_sigmoid(float x) {
  x = fminf(fmaxf(x, -30.f), 30.f);
  return 1.f / (1.f + __expf(-x));
}

// ---------------- workspace layout ----------------
// [ehi|elo (fallback only)][weight frags hi|lo][xp fp32 (big-ws path only)]
// B-frag layout (16x16x32 bf16, r7-verified): lane holds B[k=quad*8+j][n=lane&15],
// 8 contiguous bf16 per (ktg,nt,lane). ktg: W1=0..3, U1=4..11, W2=12..19, U2=20..27.
#define KT_ALL 28
#define OFF_EHI ((size_t)0)
#define OFF_ELO ((size_t)10000 * EMB_PAD * 2)
#define OFF_WHI (OFF_ELO * 2)
#define WFRAG_BYTES ((size_t)KT_ALL * 16 * 64 * 8 * 2)
#define OFF_WLO (OFF_WHI + WFRAG_BYTES)
#define WS_NEED (OFF_WLO + WFRAG_BYTES)              // 6,037,504 B (>= verified r7)
#define OFF_XP  WS_NEED
#define XP_BYTES ((size_t)BT * UNITS * 4)            // 335,544,320 B fp32
#define WS_NEED2 (OFF_XP + XP_BYTES)                 // ~341.6 MB

__device__ __forceinline__ size_t fidx(int ktg, int nt, int lane) {
  return (((size_t)ktg * 16 + nt) * 64 + lane) * 8;
}

// ---------------- precompute: weights -> swizzled bf16 hi/lo B-frags --------
__global__ __launch_bounds__(256) void k_split_w(
    const float* __restrict__ W1, const float* __restrict__ U1,
    const float* __restrict__ W2, const float* __restrict__ U2,
    u16* __restrict__ whi, u16* __restrict__ wlo)
{
  int gid = blockIdx.x * 256 + threadIdx.x;
  if (gid >= KT_ALL * 16 * 64) return;
  int lane = gid & 63, nt = (gid >> 6) & 15, ktg = gid >> 10;
  const float* M; int Kact, ktl;
  if (ktg < 4)       { M = W1; Kact = EMBD;  ktl = ktg;      }
  else if (ktg < 12) { M = U1; Kact = UNITS; ktl = ktg - 4;  }
  else if (ktg < 20) { M = W2; Kact = UNITS; ktl = ktg - 12; }
  else               { M = U2; Kact = UNITS; ktl = ktg - 20; }
  int n = nt * 16 + (lane & 15);
  int kb = ktl * 32 + (lane >> 4) * 8;
  size_t base = fidx(ktg, nt, lane);
#pragma unroll
  for (int j = 0; j < 8; ++j) {
    int k = kb + j;
    float v = (k < Kact) ? M[(size_t)k * UNITS + n] : 0.f;
    u16 hi, lo; split2(v, hi, lo);
    whi[base + j] = hi; wlo[base + j] = lo;
  }
}

// ---------------- precompute (fallback path): emb -> padded bf16 hi/lo ------
__global__ __launch_bounds__(256) void k_split_emb(
    const float* __restrict__ emb, u16* __restrict__ ehi, u16* __restrict__ elo)
{
  int gid = blockIdx.x * 256 + threadIdx.x;
  if (gid >= 10000 * EMB_PAD) return;
  int row = gid >> 7, kk = gid & (EMB_PAD - 1);
  float v = (kk < EMBD) ? emb[row * EMBD + kk] : 0.f;
  u16 hi, lo; split2(v, hi, lo);
  ehi[gid] = hi; elo[gid] = lo;
}

// ---------------- precompute (big-ws): xp[row,:] = b1 + emb[idx[row]] @ W1 --
// fp32 VALU, 16 flat rows per block (row = b*T + t). Emb-table thrash lives
// here, outside the recurrence hot loop.
__global__ __launch_bounds__(256) void k_xproj(
    const int* __restrict__ idx, const float* __restrict__ emb,
    const float* __restrict__ W1, const float* __restrict__ b1,
    float* __restrict__ xp)
{
  __shared__ float sx[16][EMBD];
  const int tid = threadIdx.x;
  const int c8 = (tid & 31) * 8;
  const int r0 = (tid >> 5) * 2;
  const size_t row0 = (size_t)blockIdx.x * 16;
  for (int i = tid; i < 16 * EMBD; i += 256) {
    int r = i / EMBD, k = i - r * EMBD;
    sx[r][k] = emb[(size_t)idx[row0 + r] * EMBD + k];
  }
  float a0[8], a1[8];
#pragma unroll
  for (int j = 0; j < 8; ++j) { a0[j] = b1[c8 + j]; a1[j] = a0[j]; }
  __syncthreads();
  for (int k = 0; k < EMBD; ++k) {
    float h0 = sx[r0][k], h1 = sx[r0 + 1][k];
    f4 w0 = *(const f4*)&W1[(size_t)k * UNITS + c8];
    f4 w1 = *(const f4*)&W1[(size_t)k * UNITS + c8 + 4];
#pragma unroll
    for (int j = 0; j < 4; ++j) {
      a0[j]     += h0 * w0[j]; a0[4 + j] += h0 * w1[j];
      a1[j]     += h1 * w0[j]; a1[4 + j] += h1 * w1[j];
    }
  }
  f4 o00 = {a0[0], a0[1], a0[2], a0[3]}, o01 = {a0[4], a0[5], a0[6], a0[7]};
  f4 o10 = {a1[0], a1[1], a1[2], a1[3]}, o11 = {a1[4], a1[5], a1[6], a1[7]};
  *(f4*)&xp[(row0 + r0) * UNITS + c8]         = o00;
  *(f4*)&xp[(row0 + r0) * UNITS + c8 + 4]     = o01;
  *(f4*)&xp[(row0 + r0 + 1) * UNITS + c8]     = o10;
  *(f4*)&xp[(row0 + r0 + 1) * UNITS + c8 + 4] = o11;
}

#define MFMA16(A, B, C) __builtin_amdgcn_mfma_f32_16x16x32_bf16(A, B, C, 0, 0, 0)

// store tanh result into next-step A-frag hi/lo (r7-verified layout)
__device__ __forceinline__ void store_frag(u16* __restrict__ fh, u16* __restrict__ fl,
                                           int col, int row, float v) {
  int a = (col >> 5) * 512 + (((col >> 3) & 3) * 16 + row) * 8 + (col & 7);
  u16 hi, lo; split2(v, hi, lo);
  fh[a] = hi; fl[a] = lo;
}

// ---------------------------------------------------------------------------
// Main kernel v3: xp streamed from ws; hot loop touches ONLY U1/W2/U2 frags
// (786 KB) + 16 KB/block-step xp. 256 blocks x 1024 thr (16 waves, 1 nt each).
// ---------------------------------------------------------------------------
__global__ __launch_bounds__(1024, 4) void rnn_mfma3(
    const float* __restrict__ xp,
    const u16* __restrict__ whi, const u16* __restrict__ wlo,
    const float* __restrict__ b2, float* __restrict__ out)
{
  __shared__ __align__(16) u16 f1[2][2][4096];
  __shared__ __align__(16) u16 f2[2][2][4096];

  const int tid  = threadIdx.x;
  const int lane = tid & 63;
  const int w    = tid >> 6;
  const int m    = lane & 15;
  const int q    = lane >> 4;
  const int col0 = w * 16 + m;
  const int b0   = blockIdx.x * 16;

  const float bias2 = b2[col0];
  // xp row pointers for this lane's 4 accumulator rows (rows q*4+r)
  const float* xpr[4];
#pragma unroll
  for (int r = 0; r < 4; ++r)
    xpr[r] = xp + ((size_t)(b0 + q * 4 + r) * TLEN) * UNITS + col0;

  for (int i = tid; i < 4096; i += 1024) {
    f1[0][0][i] = 0; f1[0][1][i] = 0;
    f2[0][0][i] = 0; f2[0][1][i] = 0;
  }
  __syncthreads();

  for (int t = 0; t < TLEN; ++t) {
    const int p = t & 1, qb = p ^ 1;

    // ---- layer 1: a = xp_t + h1 @ U1 ----  (xp loads issued first, hidden)
    float xv[4];
#pragma unroll
    for (int r = 0; r < 4; ++r) xv[r] = xpr[r][(size_t)t * UNITS];
    f32x4 acc = (f32x4){0.f, 0.f, 0.f, 0.f};
#pragma unroll
    for (int kt = 0; kt < 8; ++kt) {                 // U1 (ktg 4..11)
      const int e = kt * 512 + lane * 8;
      short8 ah = *(const short8*)&f1[p][0][e];
      short8 al = *(const short8*)&f1[p][1][e];
      short8 bh = *(const short8*)(whi + fidx(4 + kt, w, lane));
      short8 bl = *(const short8*)(wlo + fidx(4 + kt, w, lane));
      acc = MFMA16(ah, bh, acc);
      acc = MFMA16(al, bh, acc);
      acc = MFMA16(ah, bl, acc);
    }
#pragma unroll
    for (int r = 0; r < 4; ++r)
      store_frag(f1[qb][0], f1[qb][1], col0, q * 4 + r, fast_tanh(acc[r] + xv[r]));
    __syncthreads();                                 // f1[qb] visible

    // ---- layer 2: a = b2 + h1_t @ W2 + h2 @ U2 ----
    acc = (f32x4){0.f, 0.f, 0.f, 0.f};
#pragma unroll
    for (int kt = 0; kt < 8; ++kt) {                 // W2 (ktg 12..19)
      const int e = kt * 512 + lane * 8;
      short8 ah = *(const short8*)&f1[qb][0][e];
      short8 al = *(const short8*)&f1[qb][1][e];
      short8 bh = *(const short8*)(whi + fidx(12 + kt, w, lane));
      short8 bl = *(const short8*)(wlo + fidx(12 + kt, w, lane));
      acc = MFMA16(ah, bh, acc);
      acc = MFMA16(al, bh, acc);
      acc = MFMA16(ah, bl, acc);
    }
#pragma unroll
    for (int kt = 0; kt < 8; ++kt) {                 // U2 (ktg 20..27)
      const int e = kt * 512 + lane * 8;
      short8 ah = *(const short8*)&f2[p][0][e];
      short8 al = *(const short8*)&f2[p][1][e];
      short8 bh = *(const short8*)(whi + fidx(20 + kt, w, lane));
      short8 bl = *(const short8*)(wlo + fidx(20 + kt, w, lane));
      acc = MFMA16(ah, bh, acc);
      acc = MFMA16(al, bh, acc);
      acc = MFMA16(ah, bl, acc);
    }
#pragma unroll
    for (int r = 0; r < 4; ++r) {
      int row = q * 4 + r;
      float tv = fast_tanh(acc[r] + bias2);
      store_frag(f2[qb][0], f2[qb][1], col0, row, tv);
      if (t == TLEN - 1)
        out[(size_t)(b0 + row) * UNITS + col0] = fast_sigmoid(tv);
    }
    __syncthreads();                                 // f2[qb] visible
  }
}

// ---------------------------------------------------------------------------
// Fallback (r8 kernel, plain loads): used when ws_size < WS_NEED2.
// ---------------------------------------------------------------------------
__global__ __launch_bounds__(1024, 4) void rnn_mfma2(
    const int* __restrict__ idx,
    const u16* __restrict__ ehi, const u16* __restrict__ elo,
    const u16* __restrict__ whi, const u16* __restrict__ wlo,
    const float* __restrict__ b1, const float* __restrict__ b2,
    float* __restrict__ out)
{
  __shared__ __align__(16) u16 f1[2][2][4096];
  __shared__ __align__(16) u16 f2[2][2][4096];
  const int tid  = threadIdx.x;
  const int lane = tid & 63;
  const int w    = tid >> 6;
  const int m    = lane & 15;
  const int q    = lane >> 4;
  const int col0 = w * 16 + m;
  const int b0   = blockIdx.x * 16;
  const float bias1 = b1[col0];
  const float bias2 = b2[col0];
  const int* tokp = idx + (size_t)(b0 + m) * TLEN;
  for (int i = tid; i < 4096; i += 1024) {
    f1[0][0][i] = 0; f1[0][1][i] = 0;
    f2[0][0][i] = 0; f2[0][1][i] = 0;
  }
  __syncthreads();
  for (int t = 0; t < TLEN; ++t) {
    const int p = t & 1, qb = p ^ 1;
    f32x4 acc = (f32x4){0.f, 0.f, 0.f, 0.f};
    const int tok = tokp[t];
    const u16* eh = ehi + (size_t)tok * EMB_PAD + q * 8;
    const u16* el = elo + (size_t)tok * EMB_PAD + q * 8;
#pragma unroll
    for (int kt = 0; kt < 4; ++kt) {
      short8 ah = *(const short8*)(eh + kt * 32);
      short8 al = *(const short8*)(el + kt * 32);
      short8 bh = *(const short8*)(whi + fidx(kt, w, lane));
      short8 bl = *(const short8*)(wlo + fidx(kt, w, lane));
      acc = MFMA16(ah, bh, acc); acc = MFMA16(al, bh, acc); acc = MFMA16(ah, bl, acc);
    }
#pragma unroll
    for (int kt = 0; kt < 8; ++kt) {
      const int e = kt * 512 + lane * 8;
      short8 ah = *(const short8*)&f1[p][0][e];
      short8 al = *(const short8*)&f1[p][1][e];
      short8 bh = *(const short8*)(whi + fidx(4 + kt, w, lane));
      short8 bl = *(const short8*)(wlo + fidx(4 + kt, w, lane));
      acc = MFMA16(ah, bh, acc); acc = MFMA16(al, bh, acc); acc = MFMA16(ah, bl, acc);
    }
#pragma unroll
    for (int r = 0; r < 4; ++r)
      store_frag(f1[qb][0], f1[qb][1], col0, q * 4 + r, fast_tanh(acc[r] + bias1));
    __syncthreads();
    acc = (f32x4){0.f, 0.f, 0.f, 0.f};
#pragma unroll
    for (int kt = 0; kt < 8; ++kt) {
      const int e = kt * 512 + lane * 8;
      short8 ah = *(const short8*)&f1[qb][0][e];
      short8 al = *(const short8*)&f1[qb][1][e];
      short8 bh = *(const short8*)(whi + fidx(12 + kt, w, lane));
      short8 bl = *(const short8*)(wlo + fidx(12 + kt, w, lane));
      acc = MFMA16(ah, bh, acc); acc = MFMA16(al, bh, acc); acc = MFMA16(ah, bl, acc);
    }
#pragma unroll
    for (int kt = 0; kt < 8; ++kt) {
      const int e = kt * 512 + lane * 8;
      short8 ah = *(const short8*)&f2[p][0][e];
      short8 al = *(const short8*)&f2[p][1][e];
      short8 bh = *(const short8*)(whi + fidx(20 + kt, w, lane));
      short8 bl = *(const short8*)(wlo + fidx(20 + kt, w, lane));
      acc = MFMA16(ah, bh, acc); acc = MFMA16(al, bh, acc); acc = MFMA16(ah, bl, acc);
    }
#pragma unroll
    for (int r = 0; r < 4; ++r) {
      int row = q * 4 + r;
      float tv = fast_tanh(acc[r] + bias2);
      store_frag(f2[qb][0], f2[qb][1], col0, row, tv);
      if (t == TLEN - 1)
        out[(size_t)(b0 + row) * UNITS + col0] = fast_sigmoid(tv);
    }
    __syncthreads();
  }
}

// ---------------------------------------------------------------------------
extern "C" void kernel_launch(void* const* d_in, const int* in_sizes, int n_in,
                              void* d_out, int out_size, void* d_ws, size_t ws_size,
                              hipStream_t stream)
{
  const int*   idx = (const int*)d_in[0];
  const float* emb = (const float*)d_in[1];
  const float* W1  = (const float*)d_in[2];
  const float* U1  = (const float*)d_in[3];
  const float* b1  = (const float*)d_in[4];
  const float* W2  = (const float*)d_in[5];
  const float* U2  = (const float*)d_in[6];
  const float* b2  = (const float*)d_in[7];
  // d_in[8] (Wd), d_in[9] (bd) dead in reference output.
  float* out = (float*)d_out;

  u16* whi = (u16*)((char*)d_ws + OFF_WHI);
  u16* wlo = (u16*)((char*)d_ws + OFF_WLO);
  k_split_w<<<(KT_ALL * 16 * 64 + 255) / 256, 256, 0, stream>>>(W1, U1, W2, U2, whi, wlo);

  if (ws_size >= WS_NEED2) {
    float* xpw = (float*)((char*)d_ws + OFF_XP);
    k_xproj<<<BT / 16, 256, 0, stream>>>(idx, emb, W1, b1, xpw);
    rnn_mfma3<<<BATCH / 16, 1024, 0, stream>>>(xpw, whi, wlo, b2, out);
  } else {
    u16* ehi = (u16*)((char*)d_ws + OFF_EHI);
    u16* elo = (u16*)((char*)d_ws + OFF_ELO);
    k_split_emb<<<(10000 * EMB_PAD + 255) / 256, 256, 0, stream>>>(emb, ehi, elo);
    rnn_mfma2<<<BATCH / 16, 1024, 0, stream>>>(idx, ehi, elo, whi, wlo, b1, b2, out);
  }
}

// Round 10
// 635.003 us; speedup vs baseline: 29.2778x; 3.0653x over previous
//
#include <hip/hip_runtime.h>

// Problem: VOCAB=10000, EMB=100, T=80, UNITS=256, BATCH=4096 — ALL FP32 I/O.
// out = sigmoid(h2_T);  h_l,t = tanh(x_l,t @ Wl + h_l,t-1 @ Ul + bl)
#define BATCH 4096
#define TLEN  80
#define EMBD  100
#define UNITS 256
#define EMB_PAD 128            // emb K padded to 4 k-tiles of 32

typedef _Float16 f16;
typedef __attribute__((ext_vector_type(8))) _Float16 h8;   // 8 f16 = 4 VGPR MFMA A/B frag
typedef __attribute__((ext_vector_type(4))) float f32x4;   // MFMA C/D frag

__device__ __forceinline__ float fast_tanh(float x) {
  x = fminf(fmaxf(x, -15.f), 15.f);
  float e = __expf(-2.f * x);
  return (1.f - e) / (1.f + e);
}
__device__ __forceinline__ float fast_sigmoid(float x) {
  x = fminf(fmaxf(x, -30.f), 30.f);
  return 1.f / (1.f + __expf(-x));
}

// ---------------- workspace layout (3.02 MB total; ws >= 6.04 MB r7-verified)
// ehf: emb fp16 padded [10000][128]; wf: fp16 B-frags, single copy.
// B-frag layout (16x16x32, r7-verified, dtype-independent): lane holds
// B[k=quad*8+j][n=lane&15]; 8 contiguous f16 per (ktg,nt,lane) -> one dwordx4.
// ktg slots: W1 (K pad 128) = 0..3, U1 = 4..11, W2 = 12..19, U2 = 20..27.
#define KT_ALL 28
#define OFF_EHF ((size_t)0)
#define EHF_BYTES ((size_t)10000 * EMB_PAD * 2)             // 2,560,000
#define OFF_WF  EHF_BYTES
#define WF_BYTES ((size_t)KT_ALL * 16 * 64 * 8 * 2)         //   458,752
#define WS_NEED (OFF_WF + WF_BYTES)                          // 3,018,752 B

__device__ __forceinline__ size_t fidx(int ktg, int nt, int lane) {
  return (((size_t)ktg * 16 + nt) * 64 + lane) * 8;
}

// ---------------- precompute: weights -> swizzled fp16 B-frags (single) -----
__global__ __launch_bounds__(256) void k_split_w16(
    const float* __restrict__ W1, const float* __restrict__ U1,
    const float* __restrict__ W2, const float* __restrict__ U2,
    f16* __restrict__ wf)
{
  int gid = blockIdx.x * 256 + threadIdx.x;           // one per (ktg,nt,lane)
  if (gid >= KT_ALL * 16 * 64) return;
  int lane = gid & 63, nt = (gid >> 6) & 15, ktg = gid >> 10;
  const float* M; int Kact, ktl;
  if (ktg < 4)       { M = W1; Kact = EMBD;  ktl = ktg;      }
  else if (ktg < 12) { M = U1; Kact = UNITS; ktl = ktg - 4;  }
  else if (ktg < 20) { M = W2; Kact = UNITS; ktl = ktg - 12; }
  else               { M = U2; Kact = UNITS; ktl = ktg - 20; }
  int n = nt * 16 + (lane & 15);
  int kb = ktl * 32 + (lane >> 4) * 8;
  size_t base = fidx(ktg, nt, lane);
#pragma unroll
  for (int j = 0; j < 8; ++j) {
    int k = kb + j;
    wf[base + j] = (f16)((k < Kact) ? M[(size_t)k * UNITS + n] : 0.f);  // RNE
  }
}

// ---------------- precompute: emb -> padded fp16 ----------------------------
__global__ __launch_bounds__(256) void k_split_emb16(
    const float* __restrict__ emb, f16* __restrict__ ehf)
{
  int gid = blockIdx.x * 256 + threadIdx.x;
  if (gid >= 10000 * EMB_PAD) return;
  int row = gid >> 7, kk = gid & (EMB_PAD - 1);
  ehf[gid] = (f16)((kk < EMBD) ? emb[row * EMBD + kk] : 0.f);
}

#define MFMA16(A, B, C) __builtin_amdgcn_mfma_f32_16x16x32_f16(A, B, C, 0, 0, 0)

// store tanh result into next-step A-frag hi/lo (layout r7-verified):
// elem (row=m, col=k): kt=col>>5, lane'=((col>>3)&3)*16+row, j'=col&7
__device__ __forceinline__ void store_frag(f16* __restrict__ fh, f16* __restrict__ fl,
                                           int col, int row, float v) {
  int a = (col >> 5) * 512 + (((col >> 3) & 3) * 16 + row) * 8 + (col & 7);
  f16 hi = (f16)v;
  fh[a] = hi;
  fl[a] = (f16)(v - (float)hi);    // h carries ~22-bit effective mantissa
}

// ---------------------------------------------------------------------------
// Main kernel: 256 blocks (16 batch rows) x 1024 thr (16 waves; wave w owns
// n-tile w = cols [w*16, w*16+16)). Weights: single fp16 B-frag per kt, loaded
// into register ARRAYS before each MFMA chain (8-16 loads in flight/wave).
// h-state: fp16 hi/lo A-frags in LDS (2-pass MFMA per kt; B reused from regs,
// so the insurance costs no global traffic). x: single-pass fp16.
// LDS: f1 + f2 = 2 layers x 2 buf x 2 hilo x 8 KB = 64 KB.
// ---------------------------------------------------------------------------
__global__ __launch_bounds__(1024, 4) void rnn_h16(
    const int* __restrict__ idx, const f16* __restrict__ ehf,
    const f16* __restrict__ wf,
    const float* __restrict__ b1, const float* __restrict__ b2,
    float* __restrict__ out)
{
  __shared__ __align__(16) f16 f1[2][2][4096];   // [buf][hi/lo][kt*512+lane*8+j]
  __shared__ __align__(16) f16 f2[2][2][4096];

  const int tid  = threadIdx.x;
  const int lane = tid & 63;
  const int w    = tid >> 6;          // wave 0..15 = its n-tile
  const int m    = lane & 15;
  const int q    = lane >> 4;
  const int col0 = w * 16 + m;
  const int b0   = blockIdx.x * 16;

  const float bias1 = b1[col0];
  const float bias2 = b2[col0];
  const int* tokp = idx + (size_t)(b0 + m) * TLEN;

  for (int i = tid; i < 4096; i += 1024) {
    f1[0][0][i] = (f16)0.f; f1[0][1][i] = (f16)0.f;
    f2[0][0][i] = (f16)0.f; f2[0][1][i] = (f16)0.f;
  }
  __syncthreads();

  for (int t = 0; t < TLEN; ++t) {
    const int p = t & 1, qb = p ^ 1;

    // ======== layer 1: a = b1 + x_t @ W1 + h1 @ U1 ========
    const int tok = tokp[t];
    const f16* eh = ehf + (size_t)tok * EMB_PAD + q * 8;
    h8 Bx[4], Bu[8], Ax[4];
#pragma unroll
    for (int kt = 0; kt < 4; ++kt) {           // batch-issue all loads first
      Bx[kt] = *(const h8*)(wf + fidx(kt, w, lane));
      Ax[kt] = *(const h8*)(eh + kt * 32);
    }
#pragma unroll
    for (int kt = 0; kt < 8; ++kt)
      Bu[kt] = *(const h8*)(wf + fidx(4 + kt, w, lane));

    f32x4 acc = (f32x4){0.f, 0.f, 0.f, 0.f};
#pragma unroll
    for (int kt = 0; kt < 4; ++kt)             // x-part: single pass
      acc = MFMA16(Ax[kt], Bx[kt], acc);
#pragma unroll
    for (int kt = 0; kt < 8; ++kt) {           // U1-part: h hi/lo 2-pass
      const int e = kt * 512 + lane * 8;
      h8 ah = *(const h8*)&f1[p][0][e];
      h8 al = *(const h8*)&f1[p][1][e];
      acc = MFMA16(ah, Bu[kt], acc);
      acc = MFMA16(al, Bu[kt], acc);
    }
#pragma unroll
    for (int r = 0; r < 4; ++r)
      store_frag(f1[qb][0], f1[qb][1], col0, q * 4 + r, fast_tanh(acc[r] + bias1));
    __syncthreads();                           // f1[qb] visible

    // ======== layer 2: a = b2 + h1_t @ W2 + h2 @ U2 ========
    h8 Bw[8], Bu2[8];
#pragma unroll
    for (int kt = 0; kt < 8; ++kt) {
      Bw [kt] = *(const h8*)(wf + fidx(12 + kt, w, lane));
      Bu2[kt] = *(const h8*)(wf + fidx(20 + kt, w, lane));
    }
    acc = (f32x4){0.f, 0.f, 0.f, 0.f};
#pragma unroll
    for (int kt = 0; kt < 8; ++kt) {           // W2-part (A = h1 new)
      const int e = kt * 512 + lane * 8;
      h8 ah = *(const h8*)&f1[qb][0][e];
      h8 al = *(const h8*)&f1[qb][1][e];
      acc = MFMA16(ah, Bw[kt], acc);
      acc = MFMA16(al, Bw[kt], acc);
    }
#pragma unroll
    for (int kt = 0; kt < 8; ++kt) {           // U2-part (A = h2 old)
      const int e = kt * 512 + lane * 8;
      h8 ah = *(const h8*)&f2[p][0][e];
      h8 al = *(const h8*)&f2[p][1][e];
      acc = MFMA16(ah, Bu2[kt], acc);
      acc = MFMA16(al, Bu2[kt], acc);
    }
#pragma unroll
    for (int r = 0; r < 4; ++r) {
      int row = q * 4 + r;
      float tv = fast_tanh(acc[r] + bias2);
      store_frag(f2[qb][0], f2[qb][1], col0, row, tv);
      if (t == TLEN - 1)
        out[(size_t)(b0 + row) * UNITS + col0] = fast_sigmoid(tv);
    }
    __syncthreads();                           // f2[qb] visible
  }
}

// ---------------------------------------------------------------------------
extern "C" void kernel_launch(void* const* d_in, const int* in_sizes, int n_in,
                              void* d_out, int out_size, void* d_ws, size_t ws_size,
                              hipStream_t stream)
{
  const int*   idx = (const int*)d_in[0];
  const float* emb = (const float*)d_in[1];
  const float* W1  = (const float*)d_in[2];
  const float* U1  = (const float*)d_in[3];
  const float* b1  = (const float*)d_in[4];
  const float* W2  = (const float*)d_in[5];
  const float* U2  = (const float*)d_in[6];
  const float* b2  = (const float*)d_in[7];
  // d_in[8] (Wd), d_in[9] (bd) dead in the reference output.
  float* out = (float*)d_out;

  // WS_NEED = 3.02 MB < 6.04 MB proven available in round 7.
  f16* ehf = (f16*)((char*)d_ws + OFF_EHF);
  f16* wf  = (f16*)((char*)d_ws + OFF_WF);
  k_split_emb16<<<(10000 * EMB_PAD + 255) / 256, 256, 0, stream>>>(emb, ehf);
  k_split_w16<<<(KT_ALL * 16 * 64 + 255) / 256, 256, 0, stream>>>(W1, U1, W2, U2, wf);
  rnn_h16<<<BATCH / 16, 1024, 0, stream>>>(idx, ehf, wf, b1, b2, out);
}

// Round 11
// 579.245 us; speedup vs baseline: 32.0960x; 1.0963x over previous
//
#include <hip/hip_runtime.h>

// Problem: VOCAB=10000, EMB=100, T=80, UNITS=256, BATCH=4096 — ALL FP32 I/O.
// out = sigmoid(h2_T);  h_l,t = tanh(x_l,t @ Wl + h_l,t-1 @ Ul + bl)
#define BATCH 4096
#define TLEN  80
#define EMBD  100
#define UNITS 256
#define EMB_PAD 128            // emb K padded to 4 k-tiles of 32

typedef _Float16 f16;
typedef __attribute__((ext_vector_type(8))) _Float16 h8;   // 8 f16 = 4 VGPR MFMA A/B frag
typedef __attribute__((ext_vector_type(4))) float f32x4;   // MFMA C/D frag

__device__ __forceinline__ float fast_tanh(float x) {
  x = fminf(fmaxf(x, -15.f), 15.f);
  float e = __expf(-2.f * x);
  return (1.f - e) / (1.f + e);
}
__device__ __forceinline__ float fast_sigmoid(float x) {
  x = fminf(fmaxf(x, -30.f), 30.f);
  return 1.f / (1.f + __expf(-x));
}

// ---------------- workspace layout (3.02 MB; must stay < 4 MB so the hot set
// is L2-resident per XCD — r10's key lesson: 6.9 MB thrashed, 3.0 MB hits) ----
// B-frag layout (16x16x32, r7-verified, dtype-independent): lane holds
// B[k=quad*8+j][n=lane&15]; 8 contiguous f16 per (ktg,nt,lane) -> one dwordx4.
// ktg slots: W1 (K pad 128) = 0..3, U1 = 4..11, W2 = 12..19, U2 = 20..27.
#define KT_ALL 28
#define OFF_EHF ((size_t)0)
#define EHF_BYTES ((size_t)10000 * EMB_PAD * 2)             // 2,560,000
#define OFF_WF  EHF_BYTES
#define WF_BYTES ((size_t)KT_ALL * 16 * 64 * 8 * 2)         //   458,752
#define WS_NEED (OFF_WF + WF_BYTES)                          // 3,018,752 B

__device__ __forceinline__ size_t fidx(int ktg, int nt, int lane) {
  return (((size_t)ktg * 16 + nt) * 64 + lane) * 8;
}

// ---------------- precompute: weights -> swizzled fp16 B-frags (r10-verified)
__global__ __launch_bounds__(256) void k_split_w16(
    const float* __restrict__ W1, const float* __restrict__ U1,
    const float* __restrict__ W2, const float* __restrict__ U2,
    f16* __restrict__ wf)
{
  int gid = blockIdx.x * 256 + threadIdx.x;           // one per (ktg,nt,lane)
  if (gid >= KT_ALL * 16 * 64) return;
  int lane = gid & 63, nt = (gid >> 6) & 15, ktg = gid >> 10;
  const float* M; int Kact, ktl;
  if (ktg < 4)       { M = W1; Kact = EMBD;  ktl = ktg;      }
  else if (ktg < 12) { M = U1; Kact = UNITS; ktl = ktg - 4;  }
  else if (ktg < 20) { M = W2; Kact = UNITS; ktl = ktg - 12; }
  else               { M = U2; Kact = UNITS; ktl = ktg - 20; }
  int n = nt * 16 + (lane & 15);
  int kb = ktl * 32 + (lane >> 4) * 8;
  size_t base = fidx(ktg, nt, lane);
#pragma unroll
  for (int j = 0; j < 8; ++j) {
    int k = kb + j;
    wf[base + j] = (f16)((k < Kact) ? M[(size_t)k * UNITS + n] : 0.f);  // RNE
  }
}

// ---------------- precompute: emb -> padded fp16 (r10-verified) -------------
__global__ __launch_bounds__(256) void k_split_emb16(
    const float* __restrict__ emb, f16* __restrict__ ehf)
{
  int gid = blockIdx.x * 256 + threadIdx.x;
  if (gid >= 10000 * EMB_PAD) return;
  int row = gid >> 7, kk = gid & (EMB_PAD - 1);
  ehf[gid] = (f16)((kk < EMBD) ? emb[row * EMBD + kk] : 0.f);
}

#define MFMA16(A, B, C) __builtin_amdgcn_mfma_f32_16x16x32_f16(A, B, C, 0, 0, 0)

// store tanh result into next-step A-frag (single f16; layout r7-verified):
// elem (row=m, col=k): kt=col>>5, lane'=((col>>3)&3)*16+row, j'=col&7
__device__ __forceinline__ void store_frag1(f16* __restrict__ f, int col, int row, float v) {
  int a = (col >> 5) * 512 + (((col >> 3) & 3) * 16 + row) * 8 + (col & 7);
  f[a] = (f16)v;
}

// ---------------------------------------------------------------------------
// Main kernel v5: weight-stationary. 256 blocks (16 batch rows) x 1024 thr
// (16 waves; wave w owns n-tile w). All 28 B-frags live in VGPRs for the whole
// t-loop (112 VGPR persistent) — in-loop VMEM is ONLY the 4-frag emb gather.
// h states: single fp16 A-frags in LDS, double-buffered (32 KB total).
// Reordered step: [x@W1 + h1@U1 -> tanh h1 -> store] [h2@U2 pre-barrier]
// barrier [h1new@W2 -> tanh h2 -> store] barrier. Post-barrier path = 8 MFMA.
// ---------------------------------------------------------------------------
__global__ __launch_bounds__(1024) void rnn_ws(
    const int* __restrict__ idx, const f16* __restrict__ ehf,
    const f16* __restrict__ wf,
    const float* __restrict__ b1, const float* __restrict__ b2,
    float* __restrict__ out)
{
  __shared__ __align__(16) f16 f1[2][4096];   // [buf][kt*512 + lane*8 + j]
  __shared__ __align__(16) f16 f2[2][4096];

  const int tid  = threadIdx.x;
  const int lane = tid & 63;
  const int w    = tid >> 6;          // wave 0..15 = its n-tile
  const int m    = lane & 15;
  const int q    = lane >> 4;
  const int col0 = w * 16 + m;
  const int b0   = blockIdx.x * 16;

  const float bias1 = b1[col0];
  const float bias2 = b2[col0];
  const int* tokp = idx + (size_t)(b0 + m) * TLEN;

  // -------- persistent weight fragments: loaded once, live in VGPRs --------
  h8 Bx[4], Bu1[8], Bw2[8], Bu2[8];
#pragma unroll
  for (int kt = 0; kt < 4; ++kt) Bx[kt]  = *(const h8*)(wf + fidx(kt,      w, lane));
#pragma unroll
  for (int kt = 0; kt < 8; ++kt) Bu1[kt] = *(const h8*)(wf + fidx(4  + kt, w, lane));
#pragma unroll
  for (int kt = 0; kt < 8; ++kt) Bw2[kt] = *(const h8*)(wf + fidx(12 + kt, w, lane));
#pragma unroll
  for (int kt = 0; kt < 8; ++kt) Bu2[kt] = *(const h8*)(wf + fidx(20 + kt, w, lane));

  // t=0 embedding fragment (A-operand rows = this lane's token row m)
  h8 Ax[4];
  {
    const f16* eh = ehf + (size_t)tokp[0] * EMB_PAD + q * 8;
#pragma unroll
    for (int kt = 0; kt < 4; ++kt) Ax[kt] = *(const h8*)(eh + kt * 32);
  }

  for (int i = tid; i < 4096; i += 1024) {
    f1[0][i] = (f16)0.f;
    f2[0][i] = (f16)0.f;
  }
  __syncthreads();

  for (int t = 0; t < TLEN; ++t) {
    const int p = t & 1, qb = p ^ 1;

    // ---- layer 1: a1 = b1 + x_t @ W1 + h1_old @ U1  (two indep chains) ----
    f32x4 accA = (f32x4){0.f, 0.f, 0.f, 0.f};
    f32x4 accB = (f32x4){0.f, 0.f, 0.f, 0.f};
#pragma unroll
    for (int kt = 0; kt < 4; ++kt)
      accA = MFMA16(Ax[kt], Bx[kt], accA);
#pragma unroll
    for (int kt = 0; kt < 8; ++kt) {
      h8 ah = *(const h8*)&f1[p][kt * 512 + lane * 8];
      if (kt & 1) accA = MFMA16(ah, Bu1[kt], accA);
      else        accB = MFMA16(ah, Bu1[kt], accB);
    }
#pragma unroll
    for (int r = 0; r < 4; ++r)
      store_frag1(f1[qb], col0, q * 4 + r, fast_tanh(accA[r] + accB[r] + bias1));

    // ---- layer 2 pre-barrier half: h2_old @ U2 (independent of f1[qb]) ----
    f32x4 acc2a = (f32x4){0.f, 0.f, 0.f, 0.f};
    f32x4 acc2b = (f32x4){0.f, 0.f, 0.f, 0.f};
#pragma unroll
    for (int kt = 0; kt < 8; ++kt) {
      h8 ah = *(const h8*)&f2[p][kt * 512 + lane * 8];
      if (kt & 1) acc2a = MFMA16(ah, Bu2[kt], acc2a);
      else        acc2b = MFMA16(ah, Bu2[kt], acc2b);
    }
    __syncthreads();                           // barrier 1: f1[qb] visible

    // ---- layer 2 post-barrier half: h1_new @ W2 ----
#pragma unroll
    for (int kt = 0; kt < 8; ++kt) {
      h8 ah = *(const h8*)&f1[qb][kt * 512 + lane * 8];
      if (kt & 1) acc2a = MFMA16(ah, Bw2[kt], acc2a);
      else        acc2b = MFMA16(ah, Bw2[kt], acc2b);
    }
    // prefetch next step's embedding fragment (hidden under epilogue+barrier)
    if (t + 1 < TLEN) {
      const f16* eh = ehf + (size_t)tokp[t + 1] * EMB_PAD + q * 8;
#pragma unroll
      for (int kt = 0; kt < 4; ++kt) Ax[kt] = *(const h8*)(eh + kt * 32);
    }
#pragma unroll
    for (int r = 0; r < 4; ++r) {
      int row = q * 4 + r;
      float tv = fast_tanh(acc2a[r] + acc2b[r] + bias2);
      store_frag1(f2[qb], col0, row, tv);
      if (t == TLEN - 1)
        out[(size_t)(b0 + row) * UNITS + col0] = fast_sigmoid(tv);
    }
    __syncthreads();                           // barrier 2: f2[qb] visible
  }
}

// ---------------------------------------------------------------------------
extern "C" void kernel_launch(void* const* d_in, const int* in_sizes, int n_in,
                              void* d_out, int out_size, void* d_ws, size_t ws_size,
                              hipStream_t stream)
{
  const int*   idx = (const int*)d_in[0];
  const float* emb = (const float*)d_in[1];
  const float* W1  = (const float*)d_in[2];
  const float* U1  = (const float*)d_in[3];
  const float* b1  = (const float*)d_in[4];
  const float* W2  = (const float*)d_in[5];
  const float* U2  = (const float*)d_in[6];
  const float* b2  = (const float*)d_in[7];
  // d_in[8] (Wd), d_in[9] (bd) dead in the reference output.
  float* out = (float*)d_out;

  // WS_NEED = 3.02 MB < 6.04 MB proven available (r7); < 4 MB L2 per XCD.
  f16* ehf = (f16*)((char*)d_ws + OFF_EHF);
  f16* wf  = (f16*)((char*)d_ws + OFF_WF);
  k_split_emb16<<<(10000 * EMB_PAD + 255) / 256, 256, 0, stream>>>(emb, ehf);
  k_split_w16<<<(KT_ALL * 16 * 64 + 255) / 256, 256, 0, stream>>>(W1, U1, W2, U2, wf);
  rnn_ws<<<BATCH / 16, 1024, 0, stream>>>(idx, ehf, wf, b1, b2, out);
}